// Round 2
// baseline (1197.220 us; speedup 1.0000x reference)
//
#include <hip/hip_runtime.h>
#include <math.h>

// ---------------------------------------------------------------------------
// CommunityTrustGNN: 2-layer GraphSAGE (mean agg) + trust MLP head
// N=100000 nodes, E=1600000 edges, dims 64 -> 64 -> 32 -> (16 -> 1)
//
// Round 2: replace float scatter-atomics (153M of them, 900MB write-through)
// with a CSR build (2x 1.6M int atomics) + per-node register gathers.
// Layer-2 trick: p = relu(h1)@Wl2 computed per-node BEFORE aggregation
// (segment-mean commutes with the linear map) -> 32 floats/edge not 64.
// ---------------------------------------------------------------------------

#define NB_SCAN 98   // ceil(100000/1024); recomputed host-side, this is a max

// --- CSR build ---------------------------------------------------------------

__global__ __launch_bounds__(256) void k_deg(
    const int* __restrict__ dst, int* __restrict__ deg_i, int E)
{
    int e = blockIdx.x * 256 + threadIdx.x;
    if (e >= E) return;
    atomicAdd(&deg_i[dst[e]], 1);
}

// Block sums of deg_i (1024 elems/block)
__global__ __launch_bounds__(1024) void k_scan1(
    const int* __restrict__ deg_i, int* __restrict__ partials, int N)
{
    __shared__ int sWave[16];
    int i = blockIdx.x * 1024 + threadIdx.x;
    int v = (i < N) ? deg_i[i] : 0;
    #pragma unroll
    for (int off = 32; off; off >>= 1) v += __shfl_xor(v, off);
    int lane = threadIdx.x & 63, wid = threadIdx.x >> 6;
    if (lane == 0) sWave[wid] = v;
    __syncthreads();
    if (threadIdx.x == 0) {
        int s = 0;
        #pragma unroll
        for (int w = 0; w < 16; ++w) s += sWave[w];
        partials[blockIdx.x] = s;
    }
}

// Exclusive scan of block partials (single block), plus offset[N] = total.
__global__ __launch_bounds__(128) void k_scan2(
    const int* __restrict__ partials, int* __restrict__ blockoff,
    int* __restrict__ offset, int NB, int N)
{
    __shared__ int sP[NB_SCAN];
    if (threadIdx.x < NB) sP[threadIdx.x] = partials[threadIdx.x];
    __syncthreads();
    if (threadIdx.x == 0) {
        int run = 0;
        for (int b = 0; b < NB; ++b) {
            blockoff[b] = run;
            run += sP[b];
        }
        offset[N] = run;
    }
}

// Final exclusive scan: offset[i] and cursor[i] (fill cursor = copy of offset)
__global__ __launch_bounds__(1024) void k_scan3(
    const int* __restrict__ deg_i, const int* __restrict__ blockoff,
    int* __restrict__ offset, int* __restrict__ cursor, int N)
{
    __shared__ int sWave[16];
    int i = blockIdx.x * 1024 + threadIdx.x;
    int lane = threadIdx.x & 63, wid = threadIdx.x >> 6;
    int v = (i < N) ? deg_i[i] : 0;
    int incl = v;
    #pragma unroll
    for (int off = 1; off < 64; off <<= 1) {
        int t = __shfl_up(incl, off);
        if (lane >= off) incl += t;
    }
    if (lane == 63) sWave[wid] = incl;
    __syncthreads();
    if (wid == 0 && lane < 16) {
        int s = sWave[lane];
        int orig = s;
        #pragma unroll
        for (int off = 1; off < 16; off <<= 1) {
            int t = __shfl_up(s, off);
            if (lane >= off) s += t;
        }
        sWave[lane] = s - orig;   // exclusive wave offset
    }
    __syncthreads();
    if (i < N) {
        int excl = incl - v + sWave[wid] + blockoff[blockIdx.x];
        offset[i] = excl;
        cursor[i] = excl;
    }
}

__global__ __launch_bounds__(256) void k_fill(
    const int* __restrict__ src, const int* __restrict__ dst,
    int* __restrict__ cursor, int* __restrict__ adj, int E)
{
    int e = blockIdx.x * 256 + threadIdx.x;
    if (e >= E) return;
    int t = dst[e];
    int pos = atomicAdd(&cursor[t], 1);
    adj[pos] = src[e];
}

// --- Layer 1 (fused): gather-mean(x) -> SAGE1 -> relu -> p,q ----------------
// One wave per node, lane = feature dim (64).
__global__ __launch_bounds__(256) void k_l1(
    const int* __restrict__ offset, const int* __restrict__ adj,
    const float* __restrict__ x,
    const float* __restrict__ Wl1, const float* __restrict__ Wr1,
    const float* __restrict__ b1,
    const float* __restrict__ Wl2, const float* __restrict__ Wr2,
    const float* __restrict__ b2,
    float* __restrict__ p, float* __restrict__ q, int N)
{
    __shared__ float sWl1[64 * 64];
    __shared__ float sWr1[64 * 64];
    __shared__ float sWl2[64 * 32];
    __shared__ float sWr2[64 * 32];
    for (int i = threadIdx.x; i < 64 * 64; i += 256) {
        sWl1[i] = Wl1[i];
        sWr1[i] = Wr1[i];
    }
    for (int i = threadIdx.x; i < 64 * 32; i += 256) {
        sWl2[i] = Wl2[i];
        sWr2[i] = Wr2[i];
    }
    __syncthreads();

    int lane = threadIdx.x & 63;
    int wid = threadIdx.x >> 6;

    for (int n = blockIdx.x * 4 + wid; n < N; n += gridDim.x * 4) {
        int beg = offset[n], end = offset[n + 1];
        // 4-deep unrolled gather for MLP (memory-level parallelism)
        float a0 = 0.f, a1 = 0.f, a2 = 0.f, a3 = 0.f;
        int i = beg;
        for (; i + 4 <= end; i += 4) {
            int s0 = adj[i], s1 = adj[i + 1], s2 = adj[i + 2], s3 = adj[i + 3];
            a0 += x[(size_t)s0 * 64 + lane];
            a1 += x[(size_t)s1 * 64 + lane];
            a2 += x[(size_t)s2 * 64 + lane];
            a3 += x[(size_t)s3 * 64 + lane];
        }
        for (; i < end; ++i) a0 += x[(size_t)adj[i] * 64 + lane];
        float acc = (a0 + a1) + (a2 + a3);

        float invd = (end > beg) ? 1.0f / (float)(end - beg) : 1.0f;
        float a  = acc * invd;
        float xv = x[(size_t)n * 64 + lane];

        float acc1 = b1[lane];
        #pragma unroll
        for (int k = 0; k < 64; ++k) {
            acc1 += __shfl(a, k) * sWl1[k * 64 + lane]
                  + __shfl(xv, k) * sWr1[k * 64 + lane];
        }
        float h = fmaxf(acc1, 0.0f);

        int j = lane & 31;
        int half = lane >> 5;
        const float* W = half ? sWr2 : sWl2;
        float acc2 = 0.0f;
        #pragma unroll
        for (int k = 0; k < 64; ++k) acc2 += __shfl(h, k) * W[k * 32 + j];

        if (half) q[(size_t)n * 32 + j] = acc2 + b2[j];
        else      p[(size_t)n * 32 + j] = acc2;
    }
}

// --- Layer 2 (fused): gather-mean(p) + q -> out_h; trust head ---------------
// Half-wave (32 lanes) per node, 8 nodes per 256-block.
__global__ __launch_bounds__(256) void k_l2(
    const int* __restrict__ offset, const int* __restrict__ adj,
    const float* __restrict__ p, const float* __restrict__ q,
    const float* __restrict__ Wt1, const float* __restrict__ bt1,
    const float* __restrict__ Wt2, const float* __restrict__ bt2,
    float* __restrict__ out_h, float* __restrict__ out_trust, int N)
{
    __shared__ float sW1[32 * 16];
    __shared__ float sb1[16];
    __shared__ float sW2[16];
    for (int i = threadIdx.x; i < 512; i += 256) sW1[i] = Wt1[i];
    if (threadIdx.x < 16) {
        sb1[threadIdx.x] = bt1[threadIdx.x];
        sW2[threadIdx.x] = Wt2[threadIdx.x];
    }
    __syncthreads();

    int lane = threadIdx.x & 31;
    int sub = threadIdx.x >> 5;
    int n = blockIdx.x * 8 + sub;
    if (n >= N) return;

    int beg = offset[n], end = offset[n + 1];
    float a0 = 0.f, a1 = 0.f, a2 = 0.f, a3 = 0.f;
    int i = beg;
    for (; i + 4 <= end; i += 4) {
        int s0 = adj[i], s1 = adj[i + 1], s2 = adj[i + 2], s3 = adj[i + 3];
        a0 += p[(size_t)s0 * 32 + lane];
        a1 += p[(size_t)s1 * 32 + lane];
        a2 += p[(size_t)s2 * 32 + lane];
        a3 += p[(size_t)s3 * 32 + lane];
    }
    for (; i < end; ++i) a0 += p[(size_t)adj[i] * 32 + lane];
    float acc = (a0 + a1) + (a2 + a3);

    float invd = (end > beg) ? 1.0f / (float)(end - beg) : 1.0f;
    float h = acc * invd + q[(size_t)n * 32 + lane];
    out_h[(size_t)n * 32 + lane] = h;

    // trust head: t = relu(h @ Wt1 + bt1) ; trust = sigmoid(t @ Wt2 + bt2)
    int i16 = lane & 15;
    float t = sb1[i16];
    #pragma unroll
    for (int k = 0; k < 32; ++k) t += __shfl(h, k, 32) * sW1[k * 16 + i16];
    t = fmaxf(t, 0.0f);

    float z = t * sW2[i16];
    z += __shfl_xor(z, 1);
    z += __shfl_xor(z, 2);
    z += __shfl_xor(z, 4);
    z += __shfl_xor(z, 8);
    if (lane == 0) out_trust[n] = 1.0f / (1.0f + expf(-(z + bt2[0])));
}

// ---------------------------------------------------------------------------

extern "C" void kernel_launch(void* const* d_in, const int* in_sizes, int n_in,
                              void* d_out, int out_size, void* d_ws, size_t ws_size,
                              hipStream_t stream)
{
    const float* x   = (const float*)d_in[0];
    const int*   ei  = (const int*)d_in[1];   // int32 (JAX x64 disabled)
    const float* Wl1 = (const float*)d_in[2];
    const float* Wr1 = (const float*)d_in[3];
    const float* b1  = (const float*)d_in[4];
    const float* Wl2 = (const float*)d_in[5];
    const float* Wr2 = (const float*)d_in[6];
    const float* b2  = (const float*)d_in[7];
    const float* Wt1 = (const float*)d_in[8];
    const float* bt1 = (const float*)d_in[9];
    const float* Wt2 = (const float*)d_in[10];
    const float* bt2 = (const float*)d_in[11];

    const int N = in_sizes[0] / 64;   // 100000
    const int E = in_sizes[1] / 2;    // 1600000
    const int* src = ei;
    const int* dst = ei + E;
    const int NB = (N + 1023) / 1024; // 98

    // Workspace layout (all 4-byte elements)
    int* deg_i    = (int*)d_ws;                 // N
    int* offset   = deg_i + N;                  // N+1
    int* cursor   = offset + (N + 1);           // N
    int* partials = cursor + N;                 // NB
    int* blockoff = partials + NB_SCAN;         // NB
    int* adj      = blockoff + NB_SCAN;         // E
    float* p      = (float*)(adj + E);          // N*32
    float* q      = p + (size_t)N * 32;         // N*32
    // total ~33 MB

    hipMemsetAsync(deg_i, 0, (size_t)N * sizeof(int), stream);

    k_deg  <<<(E + 255) / 256, 256, 0, stream>>>(dst, deg_i, E);
    k_scan1<<<NB, 1024, 0, stream>>>(deg_i, partials, N);
    k_scan2<<<1, 128, 0, stream>>>(partials, blockoff, offset, NB, N);
    k_scan3<<<NB, 1024, 0, stream>>>(deg_i, blockoff, offset, cursor, N);
    k_fill <<<(E + 255) / 256, 256, 0, stream>>>(src, dst, cursor, adj, E);

    k_l1<<<4096, 256, 0, stream>>>(offset, adj, x, Wl1, Wr1, b1,
                                   Wl2, Wr2, b2, p, q, N);

    float* out_h     = (float*)d_out;
    float* out_trust = out_h + (size_t)N * 32;
    k_l2<<<(N + 7) / 8, 256, 0, stream>>>(offset, adj, p, q,
                                          Wt1, bt1, Wt2, bt2,
                                          out_h, out_trust, N);
}

// Round 3
// 566.034 us; speedup vs baseline: 2.1151x; 2.1151x over previous
//
#include <hip/hip_runtime.h>
#include <math.h>

// ---------------------------------------------------------------------------
// CommunityTrustGNN: 2-layer GraphSAGE (mean agg) + trust MLP head
// N=100000 nodes, E=1600000 edges, dims 64 -> 64 -> 32 -> (16 -> 1)
//
// Round 3: mean-aggregation commutes with linear maps, so ALL dense algebra
// moves into streaming GEMMs (LDS-tiled, register-blocked f32):
//   u = x@Wl1 ; v = x@Wr1+b1          -> h1 = relu(mean(u[neigh]) + v)
//   P = [h1@Wl2 | h1@(Wl2@Wt1)]       (48 cols)
//   Q = [h1@Wr2+b2 | h1@(Wr2@Wt1)+b2@Wt1+bt1]
//   h = mean(P[:,:32]) + Q[:,:32]  ;  t = relu(mean(P[:,32:]) + Q[:,32:])
//   trust = sigmoid(t . Wt2 + bt2)
// Aggregation kernels are pure gathers: no LDS, no shfl-matmul chains.
// ---------------------------------------------------------------------------

#define NB_SCAN 98   // ceil(100000/1024)

// --- CSR build (validated in round 2) ---------------------------------------

__global__ __launch_bounds__(256) void k_deg(
    const int* __restrict__ dst, int* __restrict__ deg_i, int E)
{
    int e = blockIdx.x * 256 + threadIdx.x;
    if (e >= E) return;
    atomicAdd(&deg_i[dst[e]], 1);
}

__global__ __launch_bounds__(1024) void k_scan1(
    const int* __restrict__ deg_i, int* __restrict__ partials, int N)
{
    __shared__ int sWave[16];
    int i = blockIdx.x * 1024 + threadIdx.x;
    int v = (i < N) ? deg_i[i] : 0;
    #pragma unroll
    for (int off = 32; off; off >>= 1) v += __shfl_xor(v, off);
    int lane = threadIdx.x & 63, wid = threadIdx.x >> 6;
    if (lane == 0) sWave[wid] = v;
    __syncthreads();
    if (threadIdx.x == 0) {
        int s = 0;
        #pragma unroll
        for (int w = 0; w < 16; ++w) s += sWave[w];
        partials[blockIdx.x] = s;
    }
}

__global__ __launch_bounds__(128) void k_scan2(
    const int* __restrict__ partials, int* __restrict__ blockoff,
    int* __restrict__ offset, int NB, int N)
{
    __shared__ int sP[NB_SCAN];
    if (threadIdx.x < NB) sP[threadIdx.x] = partials[threadIdx.x];
    __syncthreads();
    if (threadIdx.x == 0) {
        int run = 0;
        for (int b = 0; b < NB; ++b) {
            blockoff[b] = run;
            run += sP[b];
        }
        offset[N] = run;
    }
}

__global__ __launch_bounds__(1024) void k_scan3(
    const int* __restrict__ deg_i, const int* __restrict__ blockoff,
    int* __restrict__ offset, int* __restrict__ cursor, int N)
{
    __shared__ int sWave[16];
    int i = blockIdx.x * 1024 + threadIdx.x;
    int lane = threadIdx.x & 63, wid = threadIdx.x >> 6;
    int v = (i < N) ? deg_i[i] : 0;
    int incl = v;
    #pragma unroll
    for (int off = 1; off < 64; off <<= 1) {
        int t = __shfl_up(incl, off);
        if (lane >= off) incl += t;
    }
    if (lane == 63) sWave[wid] = incl;
    __syncthreads();
    if (wid == 0 && lane < 16) {
        int s = sWave[lane];
        int orig = s;
        #pragma unroll
        for (int off = 1; off < 16; off <<= 1) {
            int t = __shfl_up(s, off);
            if (lane >= off) s += t;
        }
        sWave[lane] = s - orig;
    }
    __syncthreads();
    if (i < N) {
        int excl = incl - v + sWave[wid] + blockoff[blockIdx.x];
        offset[i] = excl;
        cursor[i] = excl;
    }
}

__global__ __launch_bounds__(256) void k_fill(
    const int* __restrict__ src, const int* __restrict__ dst,
    int* __restrict__ cursor, int* __restrict__ adj, int E)
{
    int e = blockIdx.x * 256 + threadIdx.x;
    if (e >= E) return;
    int t = dst[e];
    int pos = atomicAdd(&cursor[t], 1);
    adj[pos] = src[e];
}

// --- weight prep: Wbig2[64][128], bias2[128] --------------------------------
// cols 0..31: Wl2 | 32..47: Wl2@Wt1 | 48..79: Wr2 | 80..95: Wr2@Wt1 | pad 0
__global__ __launch_bounds__(256) void k_wprep(
    const float* __restrict__ Wl2, const float* __restrict__ Wr2,
    const float* __restrict__ b2,
    const float* __restrict__ Wt1, const float* __restrict__ bt1,
    float* __restrict__ Wbig2, float* __restrict__ bias2)
{
    for (int i = threadIdx.x; i < 64 * 128; i += 256) {
        int k = i >> 7, n = i & 127;
        float vv = 0.0f;
        if (n < 32) {
            vv = Wl2[k * 32 + n];
        } else if (n < 48) {
            int j = n - 32;
            float s = 0.0f;
            for (int c = 0; c < 32; ++c) s += Wl2[k * 32 + c] * Wt1[c * 16 + j];
            vv = s;
        } else if (n < 80) {
            vv = Wr2[k * 32 + (n - 48)];
        } else if (n < 96) {
            int j = n - 80;
            float s = 0.0f;
            for (int c = 0; c < 32; ++c) s += Wr2[k * 32 + c] * Wt1[c * 16 + j];
            vv = s;
        }
        Wbig2[i] = vv;
    }
    if (threadIdx.x < 128) {
        int n = threadIdx.x;
        float vv = 0.0f;
        if (n >= 48 && n < 80) {
            vv = b2[n - 48];
        } else if (n >= 80 && n < 96) {
            int j = n - 80;
            float s = bt1[j];
            for (int c = 0; c < 32; ++c) s += b2[c] * Wt1[c * 16 + j];
            vv = s;
        }
        bias2[n] = vv;
    }
}

// --- GEMM1: [u|v] = x @ [Wl1|Wr1] (+ b1 on v half). M=N, K=64, Ncols=128 ----
// Block: 64-node tile, 256 threads, each thread 4 rows x 8 cols.
__global__ __launch_bounds__(256) void k_gemm1(
    const float* __restrict__ x,
    const float* __restrict__ Wl1, const float* __restrict__ Wr1,
    const float* __restrict__ b1,
    float* __restrict__ u, float* __restrict__ v, int N)
{
    __shared__ float sXT[64 * 68];   // [k][m], padded stride 68
    __shared__ float sW[64 * 128];   // [k][n]
    int tid = threadIdx.x;
    int nblk = blockIdx.x * 64;

    for (int i = tid * 4; i < 64 * 64; i += 1024) {
        int r = i >> 6, c = i & 63;
        int node = nblk + r;
        float4 xv = (node < N) ? *(const float4*)&x[(size_t)node * 64 + c]
                               : make_float4(0.f, 0.f, 0.f, 0.f);
        sXT[(c + 0) * 68 + r] = xv.x;
        sXT[(c + 1) * 68 + r] = xv.y;
        sXT[(c + 2) * 68 + r] = xv.z;
        sXT[(c + 3) * 68 + r] = xv.w;
    }
    for (int i = tid * 4; i < 64 * 128; i += 1024) {
        int k = i >> 7, n = i & 127;
        const float* Wsrc = (n < 64) ? (Wl1 + k * 64 + n) : (Wr1 + k * 64 + (n - 64));
        *(float4*)&sW[k * 128 + n] = *(const float4*)Wsrc;
    }
    __syncthreads();

    int mg = tid >> 4, ng = tid & 15;   // mg for coalesced stores within wave
    int m0 = mg * 4, n0 = ng * 8;

    float acc[4][8];
    #pragma unroll
    for (int mi = 0; mi < 4; ++mi)
        #pragma unroll
        for (int ni = 0; ni < 8; ++ni) acc[mi][ni] = 0.0f;

    #pragma unroll 8
    for (int k = 0; k < 64; ++k) {
        float4 a  = *(float4*)&sXT[k * 68 + m0];
        float4 w0 = *(float4*)&sW[k * 128 + n0];
        float4 w1 = *(float4*)&sW[k * 128 + n0 + 4];
        float av[4] = {a.x, a.y, a.z, a.w};
        float wv[8] = {w0.x, w0.y, w0.z, w0.w, w1.x, w1.y, w1.z, w1.w};
        #pragma unroll
        for (int mi = 0; mi < 4; ++mi)
            #pragma unroll
            for (int ni = 0; ni < 8; ++ni)
                acc[mi][ni] = fmaf(av[mi], wv[ni], acc[mi][ni]);
    }

    bool isV = (n0 >= 64);
    float bb[8];
    if (isV) {
        float4 b0 = *(const float4*)&b1[n0 - 64];
        float4 b4 = *(const float4*)&b1[n0 - 64 + 4];
        bb[0]=b0.x; bb[1]=b0.y; bb[2]=b0.z; bb[3]=b0.w;
        bb[4]=b4.x; bb[5]=b4.y; bb[6]=b4.z; bb[7]=b4.w;
    } else {
        #pragma unroll
        for (int j = 0; j < 8; ++j) bb[j] = 0.0f;
    }

    #pragma unroll
    for (int mi = 0; mi < 4; ++mi) {
        int node = nblk + m0 + mi;
        if (node >= N) continue;
        float* dstp = isV ? &v[(size_t)node * 64 + (n0 - 64)]
                          : &u[(size_t)node * 64 + n0];
        float4 o0 = make_float4(acc[mi][0]+bb[0], acc[mi][1]+bb[1],
                                acc[mi][2]+bb[2], acc[mi][3]+bb[3]);
        float4 o1 = make_float4(acc[mi][4]+bb[4], acc[mi][5]+bb[5],
                                acc[mi][6]+bb[6], acc[mi][7]+bb[7]);
        *(float4*)&dstp[0] = o0;
        *(float4*)&dstp[4] = o1;
    }
}

// --- agg1: h1 = relu(mean(u[neigh]) + v), written in-place over v -----------
// One wave per node, lane = dim. No LDS -> full occupancy.
__global__ __launch_bounds__(256) void k_agg1(
    const int* __restrict__ offset, const int* __restrict__ adj,
    const float* __restrict__ u, float* v /* h1 in-place */, int N)
{
    int n = blockIdx.x * 4 + (threadIdx.x >> 6);
    int lane = threadIdx.x & 63;
    if (n >= N) return;

    int beg = offset[n], end = offset[n + 1];
    float a0 = 0.f, a1 = 0.f, a2 = 0.f, a3 = 0.f;
    int i = beg;
    for (; i + 4 <= end; i += 4) {
        int s0 = adj[i], s1 = adj[i + 1], s2 = adj[i + 2], s3 = adj[i + 3];
        a0 += u[(size_t)s0 * 64 + lane];
        a1 += u[(size_t)s1 * 64 + lane];
        a2 += u[(size_t)s2 * 64 + lane];
        a3 += u[(size_t)s3 * 64 + lane];
    }
    for (; i < end; ++i) a0 += u[(size_t)adj[i] * 64 + lane];
    float acc = (a0 + a1) + (a2 + a3);

    float invd = (end > beg) ? 1.0f / (float)(end - beg) : 1.0f;
    size_t o = (size_t)n * 64 + lane;
    v[o] = fmaxf(acc * invd + v[o], 0.0f);
}

// --- GEMM2: [P|Q|pad] = h1 @ Wbig2 + bias2. K=64, Ncols=128 (96 used) -------
// P (48 cols) -> Pout (stride 48), Q (next 48) -> Qout (stride 48).
__global__ __launch_bounds__(256) void k_gemm2(
    const float* h1 /* = v buffer */,
    const float* __restrict__ Wbig2, const float* __restrict__ bias2,
    float* __restrict__ Pout, float* __restrict__ Qout, int N)
{
    __shared__ float sXT[64 * 68];
    __shared__ float sW[64 * 128];
    int tid = threadIdx.x;
    int nblk = blockIdx.x * 64;

    for (int i = tid * 4; i < 64 * 64; i += 1024) {
        int r = i >> 6, c = i & 63;
        int node = nblk + r;
        float4 xv = (node < N) ? *(const float4*)&h1[(size_t)node * 64 + c]
                               : make_float4(0.f, 0.f, 0.f, 0.f);
        sXT[(c + 0) * 68 + r] = xv.x;
        sXT[(c + 1) * 68 + r] = xv.y;
        sXT[(c + 2) * 68 + r] = xv.z;
        sXT[(c + 3) * 68 + r] = xv.w;
    }
    for (int i = tid * 4; i < 64 * 128; i += 1024) {
        *(float4*)&sW[i] = *(const float4*)&Wbig2[i];
    }
    __syncthreads();

    int mg = tid >> 4, ng = tid & 15;
    int m0 = mg * 4, n0 = ng * 8;

    float acc[4][8];
    #pragma unroll
    for (int mi = 0; mi < 4; ++mi)
        #pragma unroll
        for (int ni = 0; ni < 8; ++ni) acc[mi][ni] = 0.0f;

    #pragma unroll 8
    for (int k = 0; k < 64; ++k) {
        float4 a  = *(float4*)&sXT[k * 68 + m0];
        float4 w0 = *(float4*)&sW[k * 128 + n0];
        float4 w1 = *(float4*)&sW[k * 128 + n0 + 4];
        float av[4] = {a.x, a.y, a.z, a.w};
        float wv[8] = {w0.x, w0.y, w0.z, w0.w, w1.x, w1.y, w1.z, w1.w};
        #pragma unroll
        for (int mi = 0; mi < 4; ++mi)
            #pragma unroll
            for (int ni = 0; ni < 8; ++ni)
                acc[mi][ni] = fmaf(av[mi], wv[ni], acc[mi][ni]);
    }

    if (n0 >= 96) return;   // padded columns

    float4 b0 = *(const float4*)&bias2[n0];
    float4 b4 = *(const float4*)&bias2[n0 + 4];
    float bb[8] = {b0.x, b0.y, b0.z, b0.w, b4.x, b4.y, b4.z, b4.w};

    #pragma unroll
    for (int mi = 0; mi < 4; ++mi) {
        int node = nblk + m0 + mi;
        if (node >= N) continue;
        float o[8];
        #pragma unroll
        for (int j = 0; j < 8; ++j) o[j] = acc[mi][j] + bb[j];
        float* dstp = (n0 < 48) ? &Pout[(size_t)node * 48 + n0]
                                : &Qout[(size_t)node * 48 + (n0 - 48)];
        *(float4*)&dstp[0] = make_float4(o[0], o[1], o[2], o[3]);
        *(float4*)&dstp[4] = make_float4(o[4], o[5], o[6], o[7]);
    }
}

// --- agg2: h = mean(P[:,:32])+Q[:,:32] -> out_h; trust head on cols 32..47 --
// One wave per node; lanes 0..47 active in gather.
__global__ __launch_bounds__(256) void k_agg2(
    const int* __restrict__ offset, const int* __restrict__ adj,
    const float* __restrict__ P, const float* __restrict__ Q,
    const float* __restrict__ Wt2, const float* __restrict__ bt2,
    float* __restrict__ out_h, float* __restrict__ out_trust, int N)
{
    int n = blockIdx.x * 4 + (threadIdx.x >> 6);
    int lane = threadIdx.x & 63;
    if (n >= N) return;

    int beg = offset[n], end = offset[n + 1];
    float a0 = 0.f, a1 = 0.f, a2 = 0.f, a3 = 0.f;
    if (lane < 48) {
        int i = beg;
        for (; i + 4 <= end; i += 4) {
            int s0 = adj[i], s1 = adj[i + 1], s2 = adj[i + 2], s3 = adj[i + 3];
            a0 += P[(size_t)s0 * 48 + lane];
            a1 += P[(size_t)s1 * 48 + lane];
            a2 += P[(size_t)s2 * 48 + lane];
            a3 += P[(size_t)s3 * 48 + lane];
        }
        for (; i < end; ++i) a0 += P[(size_t)adj[i] * 48 + lane];
    }
    float acc = (a0 + a1) + (a2 + a3);
    float invd = (end > beg) ? 1.0f / (float)(end - beg) : 1.0f;

    if (lane < 32) {
        out_h[(size_t)n * 32 + lane] = acc * invd + Q[(size_t)n * 48 + lane];
    } else if (lane < 48) {
        float t = fmaxf(acc * invd + Q[(size_t)n * 48 + lane], 0.0f);
        float z = t * Wt2[lane - 32];
        z += __shfl_xor(z, 1);
        z += __shfl_xor(z, 2);
        z += __shfl_xor(z, 4);
        z += __shfl_xor(z, 8);
        if (lane == 32) out_trust[n] = 1.0f / (1.0f + expf(-(z + bt2[0])));
    }
}

// ---------------------------------------------------------------------------

extern "C" void kernel_launch(void* const* d_in, const int* in_sizes, int n_in,
                              void* d_out, int out_size, void* d_ws, size_t ws_size,
                              hipStream_t stream)
{
    const float* x   = (const float*)d_in[0];
    const int*   ei  = (const int*)d_in[1];
    const float* Wl1 = (const float*)d_in[2];
    const float* Wr1 = (const float*)d_in[3];
    const float* b1  = (const float*)d_in[4];
    const float* Wl2 = (const float*)d_in[5];
    const float* Wr2 = (const float*)d_in[6];
    const float* b2  = (const float*)d_in[7];
    const float* Wt1 = (const float*)d_in[8];
    const float* bt1 = (const float*)d_in[9];
    const float* Wt2 = (const float*)d_in[10];
    const float* bt2 = (const float*)d_in[11];

    const int N = in_sizes[0] / 64;   // 100000
    const int E = in_sizes[1] / 2;    // 1600000
    const int* src = ei;
    const int* dst = ei + E;
    const int NB = (N + 1023) / 1024; // 98

    // Workspace layout
    int* deg_i    = (int*)d_ws;                 // N
    int* offset   = deg_i + N;                  // N+1
    int* cursor   = offset + (N + 1);           // N
    int* partials = cursor + N;                 // NB_SCAN
    int* blockoff = partials + NB_SCAN;         // NB_SCAN
    int* adj      = blockoff + NB_SCAN;         // E
    float* u      = (float*)(adj + E);          // N*64   (later: P, stride 48)
    float* v      = u + (size_t)N * 64;         // N*64   (h1 in-place)
    float* Q      = v + (size_t)N * 64;         // N*48
    float* Wbig2  = Q + (size_t)N * 48;         // 64*128
    float* bias2  = Wbig2 + 64 * 128;           // 128
    // total ~78 MB

    hipMemsetAsync(deg_i, 0, (size_t)N * sizeof(int), stream);

    k_deg  <<<(E + 255) / 256, 256, 0, stream>>>(dst, deg_i, E);
    k_scan1<<<NB, 1024, 0, stream>>>(deg_i, partials, N);
    k_scan2<<<1, 128, 0, stream>>>(partials, blockoff, offset, NB, N);
    k_scan3<<<NB, 1024, 0, stream>>>(deg_i, blockoff, offset, cursor, N);
    k_fill <<<(E + 255) / 256, 256, 0, stream>>>(src, dst, cursor, adj, E);

    k_wprep<<<1, 256, 0, stream>>>(Wl2, Wr2, b2, Wt1, bt1, Wbig2, bias2);

    const int GB = (N + 63) / 64;   // 1563 GEMM tiles
    k_gemm1<<<GB, 256, 0, stream>>>(x, Wl1, Wr1, b1, u, v, N);
    k_agg1 <<<(N + 3) / 4, 256, 0, stream>>>(offset, adj, u, v, N);
    k_gemm2<<<GB, 256, 0, stream>>>(v, Wbig2, bias2, u /*P*/, Q, N);

    float* out_h     = (float*)d_out;
    float* out_trust = out_h + (size_t)N * 32;
    k_agg2 <<<(N + 3) / 4, 256, 0, stream>>>(offset, adj, u /*P*/, Q,
                                             Wt2, bt2, out_h, out_trust, N);
}

// Round 4
// 416.531 us; speedup vs baseline: 2.8743x; 1.3589x over previous
//
#include <hip/hip_runtime.h>
#include <math.h>

// ---------------------------------------------------------------------------
// CommunityTrustGNN: 2-layer GraphSAGE (mean agg) + trust MLP head
// N=100000 nodes, E=1600000 edges, dims 64 -> 64 -> 32 -> (16 -> 1)
//
// Round 4:
//  * Bucketed CSR build: edges partitioned into 512-node dst-buckets; degree
//    count + adj fill run one-block-per-bucket so cursor atomics and adj
//    writes stay in an L2-resident window (kills 16x write amplification).
//  * u and P stored bf16 (packed in GEMM epilogues): halves gather traffic
//    in both aggregation kernels. Accumulation stays f32.
// ---------------------------------------------------------------------------

#define NB_SCAN 98       // ceil(100000/1024)
#define BCAP    9216     // bucket capacity (avg 8163 for E=1.6M, +11 sigma)
#define BKCHUNK 4096     // edges per block in k_bucket

// bf16 helpers (round-to-nearest-even pack, exact unpack)
__device__ inline unsigned short f2bf(float x) {
    unsigned u = __float_as_uint(x);
    unsigned r = u + 0x7fffu + ((u >> 16) & 1u);
    return (unsigned short)(r >> 16);
}
__device__ inline unsigned pack2(float a, float b) {
    return (unsigned)f2bf(a) | ((unsigned)f2bf(b) << 16);
}
__device__ inline float bflo(unsigned u) { return __uint_as_float(u << 16); }
__device__ inline float bfhi(unsigned u) { return __uint_as_float(u & 0xffff0000u); }

// --- init: zero deg, set bucket cursors -------------------------------------
__global__ __launch_bounds__(256) void k_init(
    int* __restrict__ deg, int N, int* __restrict__ gcur, int nbuck)
{
    int i = blockIdx.x * 256 + threadIdx.x;
    if (i < N) deg[i] = 0;
    if (i < nbuck) gcur[i] = i * BCAP;
}

// --- bucket scatter: edges -> (src,dst) pairs grouped by dst>>9 -------------
__global__ __launch_bounds__(256) void k_bucket(
    const int* __restrict__ src, const int* __restrict__ dst,
    int* __restrict__ gcur, uint2* __restrict__ pairs, int E, int nbuck)
{
    __shared__ int hist[256];
    int tid = threadIdx.x;
    int e0 = blockIdx.x * BKCHUNK;
    int e1 = min(e0 + BKCHUNK, E);

    hist[tid] = 0;
    __syncthreads();
    for (int e = e0 + tid; e < e1; e += 256)
        atomicAdd(&hist[((unsigned)dst[e]) >> 9], 1);
    __syncthreads();
    if (tid < nbuck && hist[tid] > 0)
        hist[tid] = atomicAdd(&gcur[tid], hist[tid]);   // global base for this block
    __syncthreads();
    for (int e = e0 + tid; e < e1; e += 256) {
        int t = dst[e];
        int b = ((unsigned)t) >> 9;
        int pos = atomicAdd(&hist[b], 1);
        pairs[pos] = make_uint2((unsigned)src[e], (unsigned)t);
    }
}

// --- degree count, bucket-local (one block per bucket) ----------------------
__global__ __launch_bounds__(512) void k_deg2(
    const uint2* __restrict__ pairs, const int* __restrict__ gcur,
    int* __restrict__ deg)
{
    int b = blockIdx.x;
    int count = min(gcur[b] - b * BCAP, BCAP);
    const uint2* pp = pairs + (size_t)b * BCAP;
    for (int j = threadIdx.x; j < count; j += 512)
        atomicAdd(&deg[pp[j].y], 1);
}

// --- scan chain (validated rounds 2-3) --------------------------------------
__global__ __launch_bounds__(1024) void k_scan1(
    const int* __restrict__ deg_i, int* __restrict__ partials, int N)
{
    __shared__ int sWave[16];
    int i = blockIdx.x * 1024 + threadIdx.x;
    int v = (i < N) ? deg_i[i] : 0;
    #pragma unroll
    for (int off = 32; off; off >>= 1) v += __shfl_xor(v, off);
    int lane = threadIdx.x & 63, wid = threadIdx.x >> 6;
    if (lane == 0) sWave[wid] = v;
    __syncthreads();
    if (threadIdx.x == 0) {
        int s = 0;
        #pragma unroll
        for (int w = 0; w < 16; ++w) s += sWave[w];
        partials[blockIdx.x] = s;
    }
}

__global__ __launch_bounds__(128) void k_scan2(
    const int* __restrict__ partials, int* __restrict__ blockoff,
    int* __restrict__ offset, int NB, int N)
{
    __shared__ int sP[NB_SCAN];
    if (threadIdx.x < NB) sP[threadIdx.x] = partials[threadIdx.x];
    __syncthreads();
    if (threadIdx.x == 0) {
        int run = 0;
        for (int b = 0; b < NB; ++b) {
            blockoff[b] = run;
            run += sP[b];
        }
        offset[N] = run;
    }
}

__global__ __launch_bounds__(1024) void k_scan3(
    const int* __restrict__ deg_i, const int* __restrict__ blockoff,
    int* __restrict__ offset, int* __restrict__ cursor, int N)
{
    __shared__ int sWave[16];
    int i = blockIdx.x * 1024 + threadIdx.x;
    int lane = threadIdx.x & 63, wid = threadIdx.x >> 6;
    int v = (i < N) ? deg_i[i] : 0;
    int incl = v;
    #pragma unroll
    for (int off = 1; off < 64; off <<= 1) {
        int t = __shfl_up(incl, off);
        if (lane >= off) incl += t;
    }
    if (lane == 63) sWave[wid] = incl;
    __syncthreads();
    if (wid == 0 && lane < 16) {
        int s = sWave[lane];
        int orig = s;
        #pragma unroll
        for (int off = 1; off < 16; off <<= 1) {
            int t = __shfl_up(s, off);
            if (lane >= off) s += t;
        }
        sWave[lane] = s - orig;
    }
    __syncthreads();
    if (i < N) {
        int excl = incl - v + sWave[wid] + blockoff[blockIdx.x];
        offset[i] = excl;
        cursor[i] = excl;
    }
}

// --- adj fill, bucket-local (one block per bucket) --------------------------
__global__ __launch_bounds__(512) void k_fill2(
    const uint2* __restrict__ pairs, const int* __restrict__ gcur,
    int* __restrict__ cursor, int* __restrict__ adj)
{
    int b = blockIdx.x;
    int count = min(gcur[b] - b * BCAP, BCAP);
    const uint2* pp = pairs + (size_t)b * BCAP;
    for (int j = threadIdx.x; j < count; j += 512) {
        uint2 e = pp[j];
        int pos = atomicAdd(&cursor[e.y], 1);
        adj[pos] = (int)e.x;
    }
}

// --- weight prep: Wbig2[64][128], bias2[128] --------------------------------
// cols 0..31: Wl2 | 32..47: Wl2@Wt1 | 48..79: Wr2 | 80..95: Wr2@Wt1 | pad 0
__global__ __launch_bounds__(256) void k_wprep(
    const float* __restrict__ Wl2, const float* __restrict__ Wr2,
    const float* __restrict__ b2,
    const float* __restrict__ Wt1, const float* __restrict__ bt1,
    float* __restrict__ Wbig2, float* __restrict__ bias2)
{
    for (int i = threadIdx.x; i < 64 * 128; i += 256) {
        int k = i >> 7, n = i & 127;
        float vv = 0.0f;
        if (n < 32) {
            vv = Wl2[k * 32 + n];
        } else if (n < 48) {
            int j = n - 32;
            float s = 0.0f;
            for (int c = 0; c < 32; ++c) s += Wl2[k * 32 + c] * Wt1[c * 16 + j];
            vv = s;
        } else if (n < 80) {
            vv = Wr2[k * 32 + (n - 48)];
        } else if (n < 96) {
            int j = n - 80;
            float s = 0.0f;
            for (int c = 0; c < 32; ++c) s += Wr2[k * 32 + c] * Wt1[c * 16 + j];
            vv = s;
        }
        Wbig2[i] = vv;
    }
    if (threadIdx.x < 128) {
        int n = threadIdx.x;
        float vv = 0.0f;
        if (n >= 48 && n < 80) {
            vv = b2[n - 48];
        } else if (n >= 80 && n < 96) {
            int j = n - 80;
            float s = bt1[j];
            for (int c = 0; c < 32; ++c) s += b2[c] * Wt1[c * 16 + j];
            vv = s;
        }
        bias2[n] = vv;
    }
}

// --- GEMM1: u(bf16) = x@Wl1 ; v(f32) = x@Wr1 + b1 ---------------------------
__global__ __launch_bounds__(256) void k_gemm1(
    const float* __restrict__ x,
    const float* __restrict__ Wl1, const float* __restrict__ Wr1,
    const float* __restrict__ b1,
    unsigned* __restrict__ u16b, float* __restrict__ v, int N)
{
    __shared__ float sXT[64 * 68];   // [k][m], padded stride 68
    __shared__ float sW[64 * 128];   // [k][n]
    int tid = threadIdx.x;
    int nblk = blockIdx.x * 64;

    for (int i = tid * 4; i < 64 * 64; i += 1024) {
        int r = i >> 6, c = i & 63;
        int node = nblk + r;
        float4 xv = (node < N) ? *(const float4*)&x[(size_t)node * 64 + c]
                               : make_float4(0.f, 0.f, 0.f, 0.f);
        sXT[(c + 0) * 68 + r] = xv.x;
        sXT[(c + 1) * 68 + r] = xv.y;
        sXT[(c + 2) * 68 + r] = xv.z;
        sXT[(c + 3) * 68 + r] = xv.w;
    }
    for (int i = tid * 4; i < 64 * 128; i += 1024) {
        int k = i >> 7, n = i & 127;
        const float* Wsrc = (n < 64) ? (Wl1 + k * 64 + n) : (Wr1 + k * 64 + (n - 64));
        *(float4*)&sW[k * 128 + n] = *(const float4*)Wsrc;
    }
    __syncthreads();

    int mg = tid >> 4, ng = tid & 15;
    int m0 = mg * 4, n0 = ng * 8;

    float acc[4][8];
    #pragma unroll
    for (int mi = 0; mi < 4; ++mi)
        #pragma unroll
        for (int ni = 0; ni < 8; ++ni) acc[mi][ni] = 0.0f;

    #pragma unroll 8
    for (int k = 0; k < 64; ++k) {
        float4 a  = *(float4*)&sXT[k * 68 + m0];
        float4 w0 = *(float4*)&sW[k * 128 + n0];
        float4 w1 = *(float4*)&sW[k * 128 + n0 + 4];
        float av[4] = {a.x, a.y, a.z, a.w};
        float wv[8] = {w0.x, w0.y, w0.z, w0.w, w1.x, w1.y, w1.z, w1.w};
        #pragma unroll
        for (int mi = 0; mi < 4; ++mi)
            #pragma unroll
            for (int ni = 0; ni < 8; ++ni)
                acc[mi][ni] = fmaf(av[mi], wv[ni], acc[mi][ni]);
    }

    bool isV = (n0 >= 64);
    if (isV) {
        float4 b0 = *(const float4*)&b1[n0 - 64];
        float4 b4 = *(const float4*)&b1[n0 - 64 + 4];
        float bb[8] = {b0.x, b0.y, b0.z, b0.w, b4.x, b4.y, b4.z, b4.w};
        #pragma unroll
        for (int mi = 0; mi < 4; ++mi) {
            int node = nblk + m0 + mi;
            if (node >= N) continue;
            float* dstp = &v[(size_t)node * 64 + (n0 - 64)];
            *(float4*)&dstp[0] = make_float4(acc[mi][0]+bb[0], acc[mi][1]+bb[1],
                                             acc[mi][2]+bb[2], acc[mi][3]+bb[3]);
            *(float4*)&dstp[4] = make_float4(acc[mi][4]+bb[4], acc[mi][5]+bb[5],
                                             acc[mi][6]+bb[6], acc[mi][7]+bb[7]);
        }
    } else {
        #pragma unroll
        for (int mi = 0; mi < 4; ++mi) {
            int node = nblk + m0 + mi;
            if (node >= N) continue;
            uint4 pk;
            pk.x = pack2(acc[mi][0], acc[mi][1]);
            pk.y = pack2(acc[mi][2], acc[mi][3]);
            pk.z = pack2(acc[mi][4], acc[mi][5]);
            pk.w = pack2(acc[mi][6], acc[mi][7]);
            *(uint4*)&u16b[(size_t)node * 32 + (n0 >> 1)] = pk;
        }
    }
}

// --- agg1: h1 = relu(mean(u[neigh]) + v), in-place over v (bf16 gather) -----
// Half-wave (32 lanes) per node; lane covers dims 2l, 2l+1.
__global__ __launch_bounds__(256) void k_agg1(
    const int* __restrict__ offset, const int* __restrict__ adj,
    const unsigned* __restrict__ u16b, float* v, int N)
{
    int n = blockIdx.x * 8 + (threadIdx.x >> 5);
    int lane = threadIdx.x & 31;
    if (n >= N) return;

    int beg = offset[n], end = offset[n + 1];
    float lo0=0.f,hi0=0.f,lo1=0.f,hi1=0.f,lo2=0.f,hi2=0.f,lo3=0.f,hi3=0.f;
    int i = beg;
    for (; i + 4 <= end; i += 4) {
        int s0 = adj[i], s1 = adj[i+1], s2 = adj[i+2], s3 = adj[i+3];
        unsigned w0 = u16b[(size_t)s0 * 32 + lane];
        unsigned w1 = u16b[(size_t)s1 * 32 + lane];
        unsigned w2 = u16b[(size_t)s2 * 32 + lane];
        unsigned w3 = u16b[(size_t)s3 * 32 + lane];
        lo0 += bflo(w0); hi0 += bfhi(w0);
        lo1 += bflo(w1); hi1 += bfhi(w1);
        lo2 += bflo(w2); hi2 += bfhi(w2);
        lo3 += bflo(w3); hi3 += bfhi(w3);
    }
    for (; i < end; ++i) {
        unsigned w = u16b[(size_t)adj[i] * 32 + lane];
        lo0 += bflo(w); hi0 += bfhi(w);
    }
    float mlo = (lo0 + lo1) + (lo2 + lo3);
    float mhi = (hi0 + hi1) + (hi2 + hi3);
    float invd = (end > beg) ? 1.0f / (float)(end - beg) : 1.0f;

    float2* vrow = (float2*)v + (size_t)n * 32 + lane;
    float2 vv = *vrow;
    vv.x = fmaxf(mlo * invd + vv.x, 0.0f);
    vv.y = fmaxf(mhi * invd + vv.y, 0.0f);
    *vrow = vv;
}

// --- GEMM2: [P(bf16,48)|Q(f32,48)] = h1 @ Wbig2 + bias2 ---------------------
__global__ __launch_bounds__(256) void k_gemm2(
    const float* h1 /* = v buffer */,
    const float* __restrict__ Wbig2, const float* __restrict__ bias2,
    unsigned* __restrict__ P16b, float* __restrict__ Qout, int N)
{
    __shared__ float sXT[64 * 68];
    __shared__ float sW[64 * 128];
    int tid = threadIdx.x;
    int nblk = blockIdx.x * 64;

    for (int i = tid * 4; i < 64 * 64; i += 1024) {
        int r = i >> 6, c = i & 63;
        int node = nblk + r;
        float4 xv = (node < N) ? *(const float4*)&h1[(size_t)node * 64 + c]
                               : make_float4(0.f, 0.f, 0.f, 0.f);
        sXT[(c + 0) * 68 + r] = xv.x;
        sXT[(c + 1) * 68 + r] = xv.y;
        sXT[(c + 2) * 68 + r] = xv.z;
        sXT[(c + 3) * 68 + r] = xv.w;
    }
    for (int i = tid * 4; i < 64 * 128; i += 1024) {
        *(float4*)&sW[i] = *(const float4*)&Wbig2[i];
    }
    __syncthreads();

    int mg = tid >> 4, ng = tid & 15;
    int m0 = mg * 4, n0 = ng * 8;

    float acc[4][8];
    #pragma unroll
    for (int mi = 0; mi < 4; ++mi)
        #pragma unroll
        for (int ni = 0; ni < 8; ++ni) acc[mi][ni] = 0.0f;

    #pragma unroll 8
    for (int k = 0; k < 64; ++k) {
        float4 a  = *(float4*)&sXT[k * 68 + m0];
        float4 w0 = *(float4*)&sW[k * 128 + n0];
        float4 w1 = *(float4*)&sW[k * 128 + n0 + 4];
        float av[4] = {a.x, a.y, a.z, a.w};
        float wv[8] = {w0.x, w0.y, w0.z, w0.w, w1.x, w1.y, w1.z, w1.w};
        #pragma unroll
        for (int mi = 0; mi < 4; ++mi)
            #pragma unroll
            for (int ni = 0; ni < 8; ++ni)
                acc[mi][ni] = fmaf(av[mi], wv[ni], acc[mi][ni]);
    }

    if (n0 >= 96) return;   // padded columns

    if (n0 < 48) {
        // P part (bias is zero on these columns)
        #pragma unroll
        for (int mi = 0; mi < 4; ++mi) {
            int node = nblk + m0 + mi;
            if (node >= N) continue;
            uint4 pk;
            pk.x = pack2(acc[mi][0], acc[mi][1]);
            pk.y = pack2(acc[mi][2], acc[mi][3]);
            pk.z = pack2(acc[mi][4], acc[mi][5]);
            pk.w = pack2(acc[mi][6], acc[mi][7]);
            *(uint4*)&P16b[(size_t)node * 24 + (n0 >> 1)] = pk;
        }
    } else {
        float4 b0 = *(const float4*)&bias2[n0];
        float4 b4 = *(const float4*)&bias2[n0 + 4];
        float bb[8] = {b0.x, b0.y, b0.z, b0.w, b4.x, b4.y, b4.z, b4.w};
        #pragma unroll
        for (int mi = 0; mi < 4; ++mi) {
            int node = nblk + m0 + mi;
            if (node >= N) continue;
            float* dstp = &Qout[(size_t)node * 48 + (n0 - 48)];
            *(float4*)&dstp[0] = make_float4(acc[mi][0]+bb[0], acc[mi][1]+bb[1],
                                             acc[mi][2]+bb[2], acc[mi][3]+bb[3]);
            *(float4*)&dstp[4] = make_float4(acc[mi][4]+bb[4], acc[mi][5]+bb[5],
                                             acc[mi][6]+bb[6], acc[mi][7]+bb[7]);
        }
    }
}

// --- agg2: h = mean(P[:,:32])+Q[:,:32] -> out_h; trust head on cols 32..47 --
// Half-wave (32 lanes) per node; lanes 0..23 gather (48 bf16 = 24 uints).
__global__ __launch_bounds__(256) void k_agg2(
    const int* __restrict__ offset, const int* __restrict__ adj,
    const unsigned* __restrict__ P16b, const float* __restrict__ Q,
    const float* __restrict__ Wt2, const float* __restrict__ bt2,
    float* __restrict__ out_h, float* __restrict__ out_trust, int N)
{
    int n = blockIdx.x * 8 + (threadIdx.x >> 5);
    int lane = threadIdx.x & 31;
    if (n >= N) return;

    int beg = offset[n], end = offset[n + 1];
    float lo0=0.f,hi0=0.f,lo1=0.f,hi1=0.f,lo2=0.f,hi2=0.f,lo3=0.f,hi3=0.f;
    if (lane < 24) {
        int i = beg;
        for (; i + 4 <= end; i += 4) {
            int s0 = adj[i], s1 = adj[i+1], s2 = adj[i+2], s3 = adj[i+3];
            unsigned w0 = P16b[(size_t)s0 * 24 + lane];
            unsigned w1 = P16b[(size_t)s1 * 24 + lane];
            unsigned w2 = P16b[(size_t)s2 * 24 + lane];
            unsigned w3 = P16b[(size_t)s3 * 24 + lane];
            lo0 += bflo(w0); hi0 += bfhi(w0);
            lo1 += bflo(w1); hi1 += bfhi(w1);
            lo2 += bflo(w2); hi2 += bfhi(w2);
            lo3 += bflo(w3); hi3 += bfhi(w3);
        }
        for (; i < end; ++i) {
            unsigned w = P16b[(size_t)adj[i] * 24 + lane];
            lo0 += bflo(w); hi0 += bfhi(w);
        }
    }
    float invd = (end > beg) ? 1.0f / (float)(end - beg) : 1.0f;
    float mlo = ((lo0 + lo1) + (lo2 + lo3)) * invd;
    float mhi = ((hi0 + hi1) + (hi2 + hi3)) * invd;

    if (lane < 16) {
        float2 qv = ((const float2*)Q)[(size_t)n * 24 + lane];
        ((float2*)out_h)[(size_t)n * 16 + lane] =
            make_float2(mlo + qv.x, mhi + qv.y);
    } else if (lane < 24) {
        float2 qv = ((const float2*)Q)[(size_t)n * 24 + lane];
        float tlo = fmaxf(mlo + qv.x, 0.0f);
        float thi = fmaxf(mhi + qv.y, 0.0f);
        int j = (lane - 16) * 2;
        float z = tlo * Wt2[j] + thi * Wt2[j + 1];
        z += __shfl_xor(z, 1);
        z += __shfl_xor(z, 2);
        z += __shfl_xor(z, 4);
        if (lane == 16) out_trust[n] = 1.0f / (1.0f + expf(-(z + bt2[0])));
    }
}

// ---------------------------------------------------------------------------

extern "C" void kernel_launch(void* const* d_in, const int* in_sizes, int n_in,
                              void* d_out, int out_size, void* d_ws, size_t ws_size,
                              hipStream_t stream)
{
    const float* x   = (const float*)d_in[0];
    const int*   ei  = (const int*)d_in[1];
    const float* Wl1 = (const float*)d_in[2];
    const float* Wr1 = (const float*)d_in[3];
    const float* b1  = (const float*)d_in[4];
    const float* Wl2 = (const float*)d_in[5];
    const float* Wr2 = (const float*)d_in[6];
    const float* b2  = (const float*)d_in[7];
    const float* Wt1 = (const float*)d_in[8];
    const float* bt1 = (const float*)d_in[9];
    const float* Wt2 = (const float*)d_in[10];
    const float* bt2 = (const float*)d_in[11];

    const int N = in_sizes[0] / 64;   // 100000
    const int E = in_sizes[1] / 2;    // 1600000
    const int* src = ei;
    const int* dst = ei + E;
    const int NB = (N + 1023) / 1024;        // 98
    const int nbuck = (N + 511) / 512;       // 196

    // Workspace layout (16B-aligned prefix for vector loads/stores)
    uint2*    pairs  = (uint2*)d_ws;                          // nbuck*BCAP (8B each)
    unsigned* u16b   = (unsigned*)(pairs + (size_t)nbuck * BCAP);  // N*32 (bf16 x2)
    float*    v      = (float*)(u16b + (size_t)N * 32);       // N*64 (h1 in-place)
    unsigned* P16b   = (unsigned*)(v + (size_t)N * 64);       // N*24 (bf16 x2)
    float*    Q      = (float*)(P16b + (size_t)N * 24);       // N*48
    float*    Wbig2  = Q + (size_t)N * 48;                    // 64*128
    float*    bias2  = Wbig2 + 64 * 128;                      // 128
    int*      deg_i  = (int*)(bias2 + 128);                   // N
    int*      offset = deg_i + N;                             // N+1
    int*      cursor = offset + (N + 1);                      // N
    int*      partials = cursor + N;                          // NB_SCAN
    int*      blockoff = partials + NB_SCAN;                  // NB_SCAN
    int*      gcur   = blockoff + NB_SCAN;                    // nbuck
    int*      adj    = gcur + 256;                            // E
    // total ~90 MB

    k_init  <<<(N + 255) / 256, 256, 0, stream>>>(deg_i, N, gcur, nbuck);
    k_bucket<<<(E + BKCHUNK - 1) / BKCHUNK, 256, 0, stream>>>(src, dst, gcur, pairs, E, nbuck);
    k_deg2  <<<nbuck, 512, 0, stream>>>(pairs, gcur, deg_i);
    k_scan1 <<<NB, 1024, 0, stream>>>(deg_i, partials, N);
    k_scan2 <<<1, 128, 0, stream>>>(partials, blockoff, offset, NB, N);
    k_scan3 <<<NB, 1024, 0, stream>>>(deg_i, blockoff, offset, cursor, N);
    k_fill2 <<<nbuck, 512, 0, stream>>>(pairs, gcur, cursor, adj);

    k_wprep <<<1, 256, 0, stream>>>(Wl2, Wr2, b2, Wt1, bt1, Wbig2, bias2);

    const int GB = (N + 63) / 64;   // 1563 GEMM tiles
    k_gemm1<<<GB, 256, 0, stream>>>(x, Wl1, Wr1, b1, u16b, v, N);
    k_agg1 <<<(N + 7) / 8, 256, 0, stream>>>(offset, adj, u16b, v, N);
    k_gemm2<<<GB, 256, 0, stream>>>(v, Wbig2, bias2, P16b, Q, N);

    float* out_h     = (float*)d_out;
    float* out_trust = out_h + (size_t)N * 32;
    k_agg2 <<<(N + 7) / 8, 256, 0, stream>>>(offset, adj, P16b, Q,
                                             Wt2, bt2, out_h, out_trust, N);
}

// Round 5
// 292.383 us; speedup vs baseline: 4.0947x; 1.4246x over previous
//
#include <hip/hip_runtime.h>
#include <math.h>

// ---------------------------------------------------------------------------
// CommunityTrustGNN: 2-layer GraphSAGE (mean agg) + trust MLP head
// N=100000 nodes, E=1600000 edges, dims 64 -> 64 -> 32 -> (16 -> 1)
//
// Round 5:
//  * k_wprep parallelized (8 blocks, LDS-staged factors): was 67us on 1 CU.
//  * CSR tail fused into ONE bucket-local kernel (LDS histogram + LDS scan +
//    LDS-cursor fill) -> kills deg2 + 3-kernel global scan + fill + init.
//    adj is bucket-segmented (base = bucket*BCAP); per-node (beg,deg) in int2.
//  * pairs packed to one uint: src | (dst&511)<<17  (src < 2^17).
// ---------------------------------------------------------------------------

#define BCAP    9216     // bucket capacity (mean 8192 for E=1.6M, +11 sigma)
#define BKCHUNK 4096     // edges per block in k_bucket

// bf16 helpers (round-to-nearest-even pack, exact unpack)
__device__ inline unsigned short f2bf(float x) {
    unsigned u = __float_as_uint(x);
    unsigned r = u + 0x7fffu + ((u >> 16) & 1u);
    return (unsigned short)(r >> 16);
}
__device__ inline unsigned pack2(float a, float b) {
    return (unsigned)f2bf(a) | ((unsigned)f2bf(b) << 16);
}
__device__ inline float bflo(unsigned u) { return __uint_as_float(u << 16); }
__device__ inline float bfhi(unsigned u) { return __uint_as_float(u & 0xffff0000u); }

// --- bucket scatter: edges -> packed (src | local_dst<<17), grouped by dst>>9
__global__ __launch_bounds__(256) void k_bucket(
    const int* __restrict__ src, const int* __restrict__ dst,
    int* __restrict__ gcnt, unsigned* __restrict__ pairs, int E, int nbuck)
{
    __shared__ int hist[256];
    int tid = threadIdx.x;
    int e0 = blockIdx.x * BKCHUNK;
    int e1 = min(e0 + BKCHUNK, E);

    hist[tid] = 0;
    __syncthreads();
    for (int e = e0 + tid; e < e1; e += 256)
        atomicAdd(&hist[((unsigned)dst[e]) >> 9], 1);
    __syncthreads();
    if (tid < nbuck && hist[tid] > 0)
        hist[tid] = tid * BCAP + atomicAdd(&gcnt[tid], hist[tid]);
    __syncthreads();
    for (int e = e0 + tid; e < e1; e += 256) {
        int t = dst[e];
        int b = ((unsigned)t) >> 9;
        int pos = atomicAdd(&hist[b], 1);
        pairs[pos] = (unsigned)src[e] | ((unsigned)(t & 511) << 17);
    }
}

// --- fused CSR: per-bucket LDS histogram -> LDS scan -> LDS-cursor fill -----
// One block (512 thr) per bucket of 512 consecutive dst nodes.
__global__ __launch_bounds__(512) void k_csr(
    const unsigned* __restrict__ pairs, const int* __restrict__ gcnt,
    int2* __restrict__ nodeOff, int* __restrict__ adj, int N)
{
    __shared__ int hist[512];
    __shared__ int waveSum[8];
    int b = blockIdx.x;
    int tid = threadIdx.x;
    int count = min(gcnt[b], BCAP);
    const unsigned* pp = pairs + (size_t)b * BCAP;
    int base = b * BCAP;

    hist[tid] = 0;
    __syncthreads();
    for (int j = tid; j < count; j += 512)
        atomicAdd(&hist[pp[j] >> 17], 1);
    __syncthreads();

    int deg = hist[tid];
    int lane = tid & 63, wid = tid >> 6;
    int incl = deg;
    #pragma unroll
    for (int off = 1; off < 64; off <<= 1) {
        int t = __shfl_up(incl, off);
        if (lane >= off) incl += t;
    }
    if (lane == 63) waveSum[wid] = incl;
    __syncthreads();
    if (wid == 0 && lane < 8) {
        int s = waveSum[lane], orig = s;
        #pragma unroll
        for (int off = 1; off < 8; off <<= 1) {
            int t = __shfl_up(s, off);
            if (lane >= off) s += t;
        }
        waveSum[lane] = s - orig;   // exclusive wave offset
    }
    __syncthreads();
    int excl = incl - deg + waveSum[wid];

    int node = b * 512 + tid;
    if (node < N) nodeOff[node] = make_int2(base + excl, deg);
    __syncthreads();
    hist[tid] = excl;               // reuse as bucket-local cursor
    __syncthreads();

    for (int j = tid; j < count; j += 512) {
        unsigned e = pp[j];
        int pos = atomicAdd(&hist[e >> 17], 1);
        adj[base + pos] = (int)(e & 0x1FFFFu);
    }
}

// --- weight prep (parallel, LDS-staged) -------------------------------------
// Wbig2[64][128]: 0..31 Wl2 | 32..47 Wl2@Wt1 | 48..79 Wr2 | 80..95 Wr2@Wt1
__global__ __launch_bounds__(256) void k_wprep(
    const float* __restrict__ Wl2, const float* __restrict__ Wr2,
    const float* __restrict__ b2,
    const float* __restrict__ Wt1, const float* __restrict__ bt1,
    float* __restrict__ Wbig2, float* __restrict__ bias2)
{
    __shared__ float sWl2[64 * 32];
    __shared__ float sWr2[64 * 32];
    __shared__ float sWt1[32 * 16];
    for (int i = threadIdx.x; i < 64 * 32; i += 256) {
        sWl2[i] = Wl2[i];
        sWr2[i] = Wr2[i];
    }
    for (int i = threadIdx.x; i < 512; i += 256) sWt1[i] = Wt1[i];
    __syncthreads();

    int base = blockIdx.x * 1024;
    #pragma unroll
    for (int ii = 0; ii < 4; ++ii) {
        int i = base + ii * 256 + threadIdx.x;
        int k = i >> 7, n = i & 127;
        float vv = 0.0f;
        if (n < 32) {
            vv = sWl2[k * 32 + n];
        } else if (n < 48) {
            int j = n - 32;
            float s = 0.0f;
            #pragma unroll
            for (int c = 0; c < 32; ++c) s += sWl2[k * 32 + c] * sWt1[c * 16 + j];
            vv = s;
        } else if (n < 80) {
            vv = sWr2[k * 32 + (n - 48)];
        } else if (n < 96) {
            int j = n - 80;
            float s = 0.0f;
            #pragma unroll
            for (int c = 0; c < 32; ++c) s += sWr2[k * 32 + c] * sWt1[c * 16 + j];
            vv = s;
        }
        Wbig2[i] = vv;
    }

    if (blockIdx.x == 0 && threadIdx.x < 128) {
        int n = threadIdx.x;
        float vv = 0.0f;
        if (n >= 48 && n < 80) {
            vv = b2[n - 48];
        } else if (n >= 80 && n < 96) {
            int j = n - 80;
            float s = bt1[j];
            for (int c = 0; c < 32; ++c) s += b2[c] * sWt1[c * 16 + j];
            vv = s;
        }
        bias2[n] = vv;
    }
}

// --- GEMM1: u(bf16) = x@Wl1 ; v(f32) = x@Wr1 + b1 ---------------------------
__global__ __launch_bounds__(256) void k_gemm1(
    const float* __restrict__ x,
    const float* __restrict__ Wl1, const float* __restrict__ Wr1,
    const float* __restrict__ b1,
    unsigned* __restrict__ u16b, float* __restrict__ v, int N)
{
    __shared__ float sXT[64 * 68];   // [k][m], padded stride 68
    __shared__ float sW[64 * 128];   // [k][n]
    int tid = threadIdx.x;
    int nblk = blockIdx.x * 64;

    for (int i = tid * 4; i < 64 * 64; i += 1024) {
        int r = i >> 6, c = i & 63;
        int node = nblk + r;
        float4 xv = (node < N) ? *(const float4*)&x[(size_t)node * 64 + c]
                               : make_float4(0.f, 0.f, 0.f, 0.f);
        sXT[(c + 0) * 68 + r] = xv.x;
        sXT[(c + 1) * 68 + r] = xv.y;
        sXT[(c + 2) * 68 + r] = xv.z;
        sXT[(c + 3) * 68 + r] = xv.w;
    }
    for (int i = tid * 4; i < 64 * 128; i += 1024) {
        int k = i >> 7, n = i & 127;
        const float* Wsrc = (n < 64) ? (Wl1 + k * 64 + n) : (Wr1 + k * 64 + (n - 64));
        *(float4*)&sW[k * 128 + n] = *(const float4*)Wsrc;
    }
    __syncthreads();

    int mg = tid >> 4, ng = tid & 15;
    int m0 = mg * 4, n0 = ng * 8;

    float acc[4][8];
    #pragma unroll
    for (int mi = 0; mi < 4; ++mi)
        #pragma unroll
        for (int ni = 0; ni < 8; ++ni) acc[mi][ni] = 0.0f;

    #pragma unroll 8
    for (int k = 0; k < 64; ++k) {
        float4 a  = *(float4*)&sXT[k * 68 + m0];
        float4 w0 = *(float4*)&sW[k * 128 + n0];
        float4 w1 = *(float4*)&sW[k * 128 + n0 + 4];
        float av[4] = {a.x, a.y, a.z, a.w};
        float wv[8] = {w0.x, w0.y, w0.z, w0.w, w1.x, w1.y, w1.z, w1.w};
        #pragma unroll
        for (int mi = 0; mi < 4; ++mi)
            #pragma unroll
            for (int ni = 0; ni < 8; ++ni)
                acc[mi][ni] = fmaf(av[mi], wv[ni], acc[mi][ni]);
    }

    bool isV = (n0 >= 64);
    if (isV) {
        float4 b0 = *(const float4*)&b1[n0 - 64];
        float4 b4 = *(const float4*)&b1[n0 - 64 + 4];
        float bb[8] = {b0.x, b0.y, b0.z, b0.w, b4.x, b4.y, b4.z, b4.w};
        #pragma unroll
        for (int mi = 0; mi < 4; ++mi) {
            int node = nblk + m0 + mi;
            if (node >= N) continue;
            float* dstp = &v[(size_t)node * 64 + (n0 - 64)];
            *(float4*)&dstp[0] = make_float4(acc[mi][0]+bb[0], acc[mi][1]+bb[1],
                                             acc[mi][2]+bb[2], acc[mi][3]+bb[3]);
            *(float4*)&dstp[4] = make_float4(acc[mi][4]+bb[4], acc[mi][5]+bb[5],
                                             acc[mi][6]+bb[6], acc[mi][7]+bb[7]);
        }
    } else {
        #pragma unroll
        for (int mi = 0; mi < 4; ++mi) {
            int node = nblk + m0 + mi;
            if (node >= N) continue;
            uint4 pk;
            pk.x = pack2(acc[mi][0], acc[mi][1]);
            pk.y = pack2(acc[mi][2], acc[mi][3]);
            pk.z = pack2(acc[mi][4], acc[mi][5]);
            pk.w = pack2(acc[mi][6], acc[mi][7]);
            *(uint4*)&u16b[(size_t)node * 32 + (n0 >> 1)] = pk;
        }
    }
}

// --- agg1: h1 = relu(mean(u[neigh]) + v), in-place over v (bf16 gather) -----
// Half-wave (32 lanes) per node; lane covers dims 2l, 2l+1.
__global__ __launch_bounds__(256) void k_agg1(
    const int2* __restrict__ nodeOff, const int* __restrict__ adj,
    const unsigned* __restrict__ u16b, float* v, int N)
{
    int n = blockIdx.x * 8 + (threadIdx.x >> 5);
    int lane = threadIdx.x & 31;
    if (n >= N) return;

    int2 od = nodeOff[n];
    int beg = od.x, end = od.x + od.y;
    float lo0=0.f,hi0=0.f,lo1=0.f,hi1=0.f,lo2=0.f,hi2=0.f,lo3=0.f,hi3=0.f;
    int i = beg;
    for (; i + 4 <= end; i += 4) {
        int s0 = adj[i], s1 = adj[i+1], s2 = adj[i+2], s3 = adj[i+3];
        unsigned w0 = u16b[(size_t)s0 * 32 + lane];
        unsigned w1 = u16b[(size_t)s1 * 32 + lane];
        unsigned w2 = u16b[(size_t)s2 * 32 + lane];
        unsigned w3 = u16b[(size_t)s3 * 32 + lane];
        lo0 += bflo(w0); hi0 += bfhi(w0);
        lo1 += bflo(w1); hi1 += bfhi(w1);
        lo2 += bflo(w2); hi2 += bfhi(w2);
        lo3 += bflo(w3); hi3 += bfhi(w3);
    }
    for (; i < end; ++i) {
        unsigned w = u16b[(size_t)adj[i] * 32 + lane];
        lo0 += bflo(w); hi0 += bfhi(w);
    }
    float mlo = (lo0 + lo1) + (lo2 + lo3);
    float mhi = (hi0 + hi1) + (hi2 + hi3);
    float invd = (od.y > 0) ? 1.0f / (float)od.y : 1.0f;

    float2* vrow = (float2*)v + (size_t)n * 32 + lane;
    float2 vv = *vrow;
    vv.x = fmaxf(mlo * invd + vv.x, 0.0f);
    vv.y = fmaxf(mhi * invd + vv.y, 0.0f);
    *vrow = vv;
}

// --- GEMM2: [P(bf16,48)|Q(f32,48)] = h1 @ Wbig2 + bias2 ---------------------
__global__ __launch_bounds__(256) void k_gemm2(
    const float* h1 /* = v buffer */,
    const float* __restrict__ Wbig2, const float* __restrict__ bias2,
    unsigned* __restrict__ P16b, float* __restrict__ Qout, int N)
{
    __shared__ float sXT[64 * 68];
    __shared__ float sW[64 * 128];
    int tid = threadIdx.x;
    int nblk = blockIdx.x * 64;

    for (int i = tid * 4; i < 64 * 64; i += 1024) {
        int r = i >> 6, c = i & 63;
        int node = nblk + r;
        float4 xv = (node < N) ? *(const float4*)&h1[(size_t)node * 64 + c]
                               : make_float4(0.f, 0.f, 0.f, 0.f);
        sXT[(c + 0) * 68 + r] = xv.x;
        sXT[(c + 1) * 68 + r] = xv.y;
        sXT[(c + 2) * 68 + r] = xv.z;
        sXT[(c + 3) * 68 + r] = xv.w;
    }
    for (int i = tid * 4; i < 64 * 128; i += 1024) {
        *(float4*)&sW[i] = *(const float4*)&Wbig2[i];
    }
    __syncthreads();

    int mg = tid >> 4, ng = tid & 15;
    int m0 = mg * 4, n0 = ng * 8;

    float acc[4][8];
    #pragma unroll
    for (int mi = 0; mi < 4; ++mi)
        #pragma unroll
        for (int ni = 0; ni < 8; ++ni) acc[mi][ni] = 0.0f;

    #pragma unroll 8
    for (int k = 0; k < 64; ++k) {
        float4 a  = *(float4*)&sXT[k * 68 + m0];
        float4 w0 = *(float4*)&sW[k * 128 + n0];
        float4 w1 = *(float4*)&sW[k * 128 + n0 + 4];
        float av[4] = {a.x, a.y, a.z, a.w};
        float wv[8] = {w0.x, w0.y, w0.z, w0.w, w1.x, w1.y, w1.z, w1.w};
        #pragma unroll
        for (int mi = 0; mi < 4; ++mi)
            #pragma unroll
            for (int ni = 0; ni < 8; ++ni)
                acc[mi][ni] = fmaf(av[mi], wv[ni], acc[mi][ni]);
    }

    if (n0 >= 96) return;   // padded columns

    if (n0 < 48) {
        #pragma unroll
        for (int mi = 0; mi < 4; ++mi) {
            int node = nblk + m0 + mi;
            if (node >= N) continue;
            uint4 pk;
            pk.x = pack2(acc[mi][0], acc[mi][1]);
            pk.y = pack2(acc[mi][2], acc[mi][3]);
            pk.z = pack2(acc[mi][4], acc[mi][5]);
            pk.w = pack2(acc[mi][6], acc[mi][7]);
            *(uint4*)&P16b[(size_t)node * 24 + (n0 >> 1)] = pk;
        }
    } else {
        float4 b0 = *(const float4*)&bias2[n0];
        float4 b4 = *(const float4*)&bias2[n0 + 4];
        float bb[8] = {b0.x, b0.y, b0.z, b0.w, b4.x, b4.y, b4.z, b4.w};
        #pragma unroll
        for (int mi = 0; mi < 4; ++mi) {
            int node = nblk + m0 + mi;
            if (node >= N) continue;
            float* dstp = &Qout[(size_t)node * 48 + (n0 - 48)];
            *(float4*)&dstp[0] = make_float4(acc[mi][0]+bb[0], acc[mi][1]+bb[1],
                                             acc[mi][2]+bb[2], acc[mi][3]+bb[3]);
            *(float4*)&dstp[4] = make_float4(acc[mi][4]+bb[4], acc[mi][5]+bb[5],
                                             acc[mi][6]+bb[6], acc[mi][7]+bb[7]);
        }
    }
}

// --- agg2: h = mean(P[:,:32])+Q[:,:32] -> out_h; trust head on cols 32..47 --
// Half-wave (32 lanes) per node; lanes 0..23 gather (48 bf16 = 24 uints).
__global__ __launch_bounds__(256) void k_agg2(
    const int2* __restrict__ nodeOff, const int* __restrict__ adj,
    const unsigned* __restrict__ P16b, const float* __restrict__ Q,
    const float* __restrict__ Wt2, const float* __restrict__ bt2,
    float* __restrict__ out_h, float* __restrict__ out_trust, int N)
{
    int n = blockIdx.x * 8 + (threadIdx.x >> 5);
    int lane = threadIdx.x & 31;
    if (n >= N) return;

    int2 od = nodeOff[n];
    int beg = od.x, end = od.x + od.y;
    float lo0=0.f,hi0=0.f,lo1=0.f,hi1=0.f,lo2=0.f,hi2=0.f,lo3=0.f,hi3=0.f;
    if (lane < 24) {
        int i = beg;
        for (; i + 4 <= end; i += 4) {
            int s0 = adj[i], s1 = adj[i+1], s2 = adj[i+2], s3 = adj[i+3];
            unsigned w0 = P16b[(size_t)s0 * 24 + lane];
            unsigned w1 = P16b[(size_t)s1 * 24 + lane];
            unsigned w2 = P16b[(size_t)s2 * 24 + lane];
            unsigned w3 = P16b[(size_t)s3 * 24 + lane];
            lo0 += bflo(w0); hi0 += bfhi(w0);
            lo1 += bflo(w1); hi1 += bfhi(w1);
            lo2 += bflo(w2); hi2 += bfhi(w2);
            lo3 += bflo(w3); hi3 += bfhi(w3);
        }
        for (; i < end; ++i) {
            unsigned w = P16b[(size_t)adj[i] * 24 + lane];
            lo0 += bflo(w); hi0 += bfhi(w);
        }
    }
    float invd = (od.y > 0) ? 1.0f / (float)od.y : 1.0f;
    float mlo = ((lo0 + lo1) + (lo2 + lo3)) * invd;
    float mhi = ((hi0 + hi1) + (hi2 + hi3)) * invd;

    if (lane < 16) {
        float2 qv = ((const float2*)Q)[(size_t)n * 24 + lane];
        ((float2*)out_h)[(size_t)n * 16 + lane] =
            make_float2(mlo + qv.x, mhi + qv.y);
    } else if (lane < 24) {
        float2 qv = ((const float2*)Q)[(size_t)n * 24 + lane];
        float tlo = fmaxf(mlo + qv.x, 0.0f);
        float thi = fmaxf(mhi + qv.y, 0.0f);
        int j = (lane - 16) * 2;
        float z = tlo * Wt2[j] + thi * Wt2[j + 1];
        z += __shfl_xor(z, 1);
        z += __shfl_xor(z, 2);
        z += __shfl_xor(z, 4);
        if (lane == 16) out_trust[n] = 1.0f / (1.0f + expf(-(z + bt2[0])));
    }
}

// ---------------------------------------------------------------------------

extern "C" void kernel_launch(void* const* d_in, const int* in_sizes, int n_in,
                              void* d_out, int out_size, void* d_ws, size_t ws_size,
                              hipStream_t stream)
{
    const float* x   = (const float*)d_in[0];
    const int*   ei  = (const int*)d_in[1];
    const float* Wl1 = (const float*)d_in[2];
    const float* Wr1 = (const float*)d_in[3];
    const float* b1  = (const float*)d_in[4];
    const float* Wl2 = (const float*)d_in[5];
    const float* Wr2 = (const float*)d_in[6];
    const float* b2  = (const float*)d_in[7];
    const float* Wt1 = (const float*)d_in[8];
    const float* bt1 = (const float*)d_in[9];
    const float* Wt2 = (const float*)d_in[10];
    const float* bt2 = (const float*)d_in[11];

    const int N = in_sizes[0] / 64;   // 100000
    const int E = in_sizes[1] / 2;    // 1600000
    const int* src = ei;
    const int* dst = ei + E;
    const int nbuck = (N + 511) / 512;       // 196

    // Workspace layout (16B-aligned segments)
    unsigned* pairs  = (unsigned*)d_ws;                        // nbuck*BCAP
    unsigned* u16b   = pairs + (size_t)nbuck * BCAP;           // N*32 (bf16 x2)
    float*    v      = (float*)(u16b + (size_t)N * 32);        // N*64 (h1 in-place)
    unsigned* P16b   = (unsigned*)(v + (size_t)N * 64);        // N*24 (bf16 x2)
    float*    Q      = (float*)(P16b + (size_t)N * 24);        // N*48
    float*    Wbig2  = Q + (size_t)N * 48;                     // 64*128
    float*    bias2  = Wbig2 + 64 * 128;                       // 128
    int*      gcnt   = (int*)(bias2 + 128);                    // 256 (196 used)
    int2*     nodeOff= (int2*)(gcnt + 256);                    // N
    int*      adj    = (int*)(nodeOff + N);                    // nbuck*BCAP
    // total ~60 MB

    hipMemsetAsync(gcnt, 0, 256 * sizeof(int), stream);

    k_bucket<<<(E + BKCHUNK - 1) / BKCHUNK, 256, 0, stream>>>(src, dst, gcnt, pairs, E, nbuck);
    k_csr   <<<nbuck, 512, 0, stream>>>(pairs, gcnt, nodeOff, adj, N);
    k_wprep <<<8, 256, 0, stream>>>(Wl2, Wr2, b2, Wt1, bt1, Wbig2, bias2);

    const int GB = (N + 63) / 64;   // 1563 GEMM tiles
    k_gemm1<<<GB, 256, 0, stream>>>(x, Wl1, Wr1, b1, u16b, v, N);
    k_agg1 <<<(N + 7) / 8, 256, 0, stream>>>(nodeOff, adj, u16b, v, N);
    k_gemm2<<<GB, 256, 0, stream>>>(v, Wbig2, bias2, P16b, Q, N);

    float* out_h     = (float*)d_out;
    float* out_trust = out_h + (size_t)N * 32;
    k_agg2 <<<(N + 7) / 8, 256, 0, stream>>>(nodeOff, adj, P16b, Q,
                                             Wt2, bt2, out_h, out_trust, N);
}

// Round 6
// 264.368 us; speedup vs baseline: 4.5286x; 1.1060x over previous
//
#include <hip/hip_runtime.h>
#include <math.h>

// ---------------------------------------------------------------------------
// CommunityTrustGNN: 2-layer GraphSAGE (mean agg) + trust MLP head
// N=100000 nodes, E=1600000 edges, dims 64 -> 64 -> 32 -> (16 -> 1)
//
// Round 6:
//  * Un-fold the trust head from the layer-2 GEMM: P rows shrink 96B -> 64B
//    (exactly ONE aligned cache line per edge gather in agg2; round 5 showed
//    112MB fetched for a 9.6MB array due to 2.5-line straddle + no L2 reuse).
//    t = relu(h@Wt1+bt1) is computed per-node in agg2 via shfl (latency-bound
//    kernel, the extra VALU is free).
//  * k_wprep deleted; gemm2 reads Wl2|Wr2 directly, LDS 49->33KB (4 blk/CU).
// ---------------------------------------------------------------------------

#define BCAP    9216     // bucket capacity (mean 8192 for E=1.6M, +11 sigma)
#define BKCHUNK 4096     // edges per block in k_bucket

// bf16 helpers (round-to-nearest-even pack, exact unpack)
__device__ inline unsigned short f2bf(float x) {
    unsigned u = __float_as_uint(x);
    unsigned r = u + 0x7fffu + ((u >> 16) & 1u);
    return (unsigned short)(r >> 16);
}
__device__ inline unsigned pack2(float a, float b) {
    return (unsigned)f2bf(a) | ((unsigned)f2bf(b) << 16);
}
__device__ inline float bflo(unsigned u) { return __uint_as_float(u << 16); }
__device__ inline float bfhi(unsigned u) { return __uint_as_float(u & 0xffff0000u); }

// --- bucket scatter: edges -> packed (src | local_dst<<17), grouped by dst>>9
__global__ __launch_bounds__(256) void k_bucket(
    const int* __restrict__ src, const int* __restrict__ dst,
    int* __restrict__ gcnt, unsigned* __restrict__ pairs, int E, int nbuck)
{
    __shared__ int hist[256];
    int tid = threadIdx.x;
    int e0 = blockIdx.x * BKCHUNK;
    int e1 = min(e0 + BKCHUNK, E);

    hist[tid] = 0;
    __syncthreads();
    for (int e = e0 + tid; e < e1; e += 256)
        atomicAdd(&hist[((unsigned)dst[e]) >> 9], 1);
    __syncthreads();
    if (tid < nbuck && hist[tid] > 0)
        hist[tid] = tid * BCAP + atomicAdd(&gcnt[tid], hist[tid]);
    __syncthreads();
    for (int e = e0 + tid; e < e1; e += 256) {
        int t = dst[e];
        int b = ((unsigned)t) >> 9;
        int pos = atomicAdd(&hist[b], 1);
        pairs[pos] = (unsigned)src[e] | ((unsigned)(t & 511) << 17);
    }
}

// --- fused CSR: per-bucket LDS histogram -> LDS scan -> LDS-cursor fill -----
// One block (512 thr) per bucket of 512 consecutive dst nodes.
__global__ __launch_bounds__(512) void k_csr(
    const unsigned* __restrict__ pairs, const int* __restrict__ gcnt,
    int2* __restrict__ nodeOff, int* __restrict__ adj, int N)
{
    __shared__ int hist[512];
    __shared__ int waveSum[8];
    int b = blockIdx.x;
    int tid = threadIdx.x;
    int count = min(gcnt[b], BCAP);
    const unsigned* pp = pairs + (size_t)b * BCAP;
    int base = b * BCAP;

    hist[tid] = 0;
    __syncthreads();
    for (int j = tid; j < count; j += 512)
        atomicAdd(&hist[pp[j] >> 17], 1);
    __syncthreads();

    int deg = hist[tid];
    int lane = tid & 63, wid = tid >> 6;
    int incl = deg;
    #pragma unroll
    for (int off = 1; off < 64; off <<= 1) {
        int t = __shfl_up(incl, off);
        if (lane >= off) incl += t;
    }
    if (lane == 63) waveSum[wid] = incl;
    __syncthreads();
    if (wid == 0 && lane < 8) {
        int s = waveSum[lane], orig = s;
        #pragma unroll
        for (int off = 1; off < 8; off <<= 1) {
            int t = __shfl_up(s, off);
            if (lane >= off) s += t;
        }
        waveSum[lane] = s - orig;   // exclusive wave offset
    }
    __syncthreads();
    int excl = incl - deg + waveSum[wid];

    int node = b * 512 + tid;
    if (node < N) nodeOff[node] = make_int2(base + excl, deg);
    __syncthreads();
    hist[tid] = excl;               // reuse as bucket-local cursor
    __syncthreads();

    for (int j = tid; j < count; j += 512) {
        unsigned e = pp[j];
        int pos = atomicAdd(&hist[e >> 17], 1);
        adj[base + pos] = (int)(e & 0x1FFFFu);
    }
}

// --- GEMM1: u(bf16) = x@Wl1 ; v(f32) = x@Wr1 + b1 ---------------------------
__global__ __launch_bounds__(256) void k_gemm1(
    const float* __restrict__ x,
    const float* __restrict__ Wl1, const float* __restrict__ Wr1,
    const float* __restrict__ b1,
    unsigned* __restrict__ u16b, float* __restrict__ v, int N)
{
    __shared__ float sXT[64 * 68];   // [k][m], padded stride 68
    __shared__ float sW[64 * 128];   // [k][n]
    int tid = threadIdx.x;
    int nblk = blockIdx.x * 64;

    for (int i = tid * 4; i < 64 * 64; i += 1024) {
        int r = i >> 6, c = i & 63;
        int node = nblk + r;
        float4 xv = (node < N) ? *(const float4*)&x[(size_t)node * 64 + c]
                               : make_float4(0.f, 0.f, 0.f, 0.f);
        sXT[(c + 0) * 68 + r] = xv.x;
        sXT[(c + 1) * 68 + r] = xv.y;
        sXT[(c + 2) * 68 + r] = xv.z;
        sXT[(c + 3) * 68 + r] = xv.w;
    }
    for (int i = tid * 4; i < 64 * 128; i += 1024) {
        int k = i >> 7, n = i & 127;
        const float* Wsrc = (n < 64) ? (Wl1 + k * 64 + n) : (Wr1 + k * 64 + (n - 64));
        *(float4*)&sW[k * 128 + n] = *(const float4*)Wsrc;
    }
    __syncthreads();

    int mg = tid >> 4, ng = tid & 15;
    int m0 = mg * 4, n0 = ng * 8;

    float acc[4][8];
    #pragma unroll
    for (int mi = 0; mi < 4; ++mi)
        #pragma unroll
        for (int ni = 0; ni < 8; ++ni) acc[mi][ni] = 0.0f;

    #pragma unroll 8
    for (int k = 0; k < 64; ++k) {
        float4 a  = *(float4*)&sXT[k * 68 + m0];
        float4 w0 = *(float4*)&sW[k * 128 + n0];
        float4 w1 = *(float4*)&sW[k * 128 + n0 + 4];
        float av[4] = {a.x, a.y, a.z, a.w};
        float wv[8] = {w0.x, w0.y, w0.z, w0.w, w1.x, w1.y, w1.z, w1.w};
        #pragma unroll
        for (int mi = 0; mi < 4; ++mi)
            #pragma unroll
            for (int ni = 0; ni < 8; ++ni)
                acc[mi][ni] = fmaf(av[mi], wv[ni], acc[mi][ni]);
    }

    bool isV = (n0 >= 64);
    if (isV) {
        float4 b0 = *(const float4*)&b1[n0 - 64];
        float4 b4 = *(const float4*)&b1[n0 - 64 + 4];
        float bb[8] = {b0.x, b0.y, b0.z, b0.w, b4.x, b4.y, b4.z, b4.w};
        #pragma unroll
        for (int mi = 0; mi < 4; ++mi) {
            int node = nblk + m0 + mi;
            if (node >= N) continue;
            float* dstp = &v[(size_t)node * 64 + (n0 - 64)];
            *(float4*)&dstp[0] = make_float4(acc[mi][0]+bb[0], acc[mi][1]+bb[1],
                                             acc[mi][2]+bb[2], acc[mi][3]+bb[3]);
            *(float4*)&dstp[4] = make_float4(acc[mi][4]+bb[4], acc[mi][5]+bb[5],
                                             acc[mi][6]+bb[6], acc[mi][7]+bb[7]);
        }
    } else {
        #pragma unroll
        for (int mi = 0; mi < 4; ++mi) {
            int node = nblk + m0 + mi;
            if (node >= N) continue;
            uint4 pk;
            pk.x = pack2(acc[mi][0], acc[mi][1]);
            pk.y = pack2(acc[mi][2], acc[mi][3]);
            pk.z = pack2(acc[mi][4], acc[mi][5]);
            pk.w = pack2(acc[mi][6], acc[mi][7]);
            *(uint4*)&u16b[(size_t)node * 32 + (n0 >> 1)] = pk;
        }
    }
}

// --- agg1: h1 = relu(mean(u[neigh]) + v), in-place over v (bf16 gather) -----
// Half-wave (32 lanes) per node; lane covers dims 2l, 2l+1.
__global__ __launch_bounds__(256) void k_agg1(
    const int2* __restrict__ nodeOff, const int* __restrict__ adj,
    const unsigned* __restrict__ u16b, float* v, int N)
{
    int n = blockIdx.x * 8 + (threadIdx.x >> 5);
    int lane = threadIdx.x & 31;
    if (n >= N) return;

    int2 od = nodeOff[n];
    int beg = od.x, end = od.x + od.y;
    float lo0=0.f,hi0=0.f,lo1=0.f,hi1=0.f,lo2=0.f,hi2=0.f,lo3=0.f,hi3=0.f;
    int i = beg;
    for (; i + 4 <= end; i += 4) {
        int s0 = adj[i], s1 = adj[i+1], s2 = adj[i+2], s3 = adj[i+3];
        unsigned w0 = u16b[(size_t)s0 * 32 + lane];
        unsigned w1 = u16b[(size_t)s1 * 32 + lane];
        unsigned w2 = u16b[(size_t)s2 * 32 + lane];
        unsigned w3 = u16b[(size_t)s3 * 32 + lane];
        lo0 += bflo(w0); hi0 += bfhi(w0);
        lo1 += bflo(w1); hi1 += bfhi(w1);
        lo2 += bflo(w2); hi2 += bfhi(w2);
        lo3 += bflo(w3); hi3 += bfhi(w3);
    }
    for (; i < end; ++i) {
        unsigned w = u16b[(size_t)adj[i] * 32 + lane];
        lo0 += bflo(w); hi0 += bfhi(w);
    }
    float mlo = (lo0 + lo1) + (lo2 + lo3);
    float mhi = (hi0 + hi1) + (hi2 + hi3);
    float invd = (od.y > 0) ? 1.0f / (float)od.y : 1.0f;

    float2* vrow = (float2*)v + (size_t)n * 32 + lane;
    float2 vv = *vrow;
    vv.x = fmaxf(mlo * invd + vv.x, 0.0f);
    vv.y = fmaxf(mhi * invd + vv.y, 0.0f);
    *vrow = vv;
}

// --- GEMM2: P(bf16,32) = h1@Wl2 ; Q(f32,32) = h1@Wr2 + b2 -------------------
// 64-node tile x 64 cols, 256 threads, 4 rows x 4 cols per thread.
__global__ __launch_bounds__(256) void k_gemm2(
    const float* h1 /* = v buffer */,
    const float* __restrict__ Wl2, const float* __restrict__ Wr2,
    const float* __restrict__ b2,
    unsigned* __restrict__ P16b, float* __restrict__ Qout, int N)
{
    __shared__ float sXT[64 * 68];   // [k][m]
    __shared__ float sW[64 * 64];    // [k][n]: 0..31 Wl2, 32..63 Wr2
    int tid = threadIdx.x;
    int nblk = blockIdx.x * 64;

    for (int i = tid * 4; i < 64 * 64; i += 1024) {
        int r = i >> 6, c = i & 63;
        int node = nblk + r;
        float4 xv = (node < N) ? *(const float4*)&h1[(size_t)node * 64 + c]
                               : make_float4(0.f, 0.f, 0.f, 0.f);
        sXT[(c + 0) * 68 + r] = xv.x;
        sXT[(c + 1) * 68 + r] = xv.y;
        sXT[(c + 2) * 68 + r] = xv.z;
        sXT[(c + 3) * 68 + r] = xv.w;
    }
    for (int i = tid * 4; i < 64 * 64; i += 1024) {
        int k = i >> 6, n = i & 63;
        const float* Wsrc = (n < 32) ? (Wl2 + k * 32 + n) : (Wr2 + k * 32 + (n - 32));
        *(float4*)&sW[k * 64 + n] = *(const float4*)Wsrc;
    }
    __syncthreads();

    int mg = tid >> 4, ng = tid & 15;
    int m0 = mg * 4, n0 = ng * 4;

    float acc[4][4];
    #pragma unroll
    for (int mi = 0; mi < 4; ++mi)
        #pragma unroll
        for (int ni = 0; ni < 4; ++ni) acc[mi][ni] = 0.0f;

    #pragma unroll 8
    for (int k = 0; k < 64; ++k) {
        float4 a = *(float4*)&sXT[k * 68 + m0];
        float4 w = *(float4*)&sW[k * 64 + n0];
        float av[4] = {a.x, a.y, a.z, a.w};
        float wv[4] = {w.x, w.y, w.z, w.w};
        #pragma unroll
        for (int mi = 0; mi < 4; ++mi)
            #pragma unroll
            for (int ni = 0; ni < 4; ++ni)
                acc[mi][ni] = fmaf(av[mi], wv[ni], acc[mi][ni]);
    }

    if (n0 < 32) {
        #pragma unroll
        for (int mi = 0; mi < 4; ++mi) {
            int node = nblk + m0 + mi;
            if (node >= N) continue;
            uint2 pk;
            pk.x = pack2(acc[mi][0], acc[mi][1]);
            pk.y = pack2(acc[mi][2], acc[mi][3]);
            *(uint2*)&P16b[(size_t)node * 16 + (n0 >> 1)] = pk;
        }
    } else {
        float4 b0 = *(const float4*)&b2[n0 - 32];
        #pragma unroll
        for (int mi = 0; mi < 4; ++mi) {
            int node = nblk + m0 + mi;
            if (node >= N) continue;
            *(float4*)&Qout[(size_t)node * 32 + (n0 - 32)] =
                make_float4(acc[mi][0]+b0.x, acc[mi][1]+b0.y,
                            acc[mi][2]+b0.z, acc[mi][3]+b0.w);
        }
    }
}

// --- agg2: h = mean(P[neigh]) + Q -> out_h ; trust head in-register ---------
// 16 lanes per node (lane = 1 uint = 2 cols); 64B fully-coalesced edge gather.
__global__ __launch_bounds__(256) void k_agg2(
    const int2* __restrict__ nodeOff, const int* __restrict__ adj,
    const unsigned* __restrict__ P16b, const float* __restrict__ Q,
    const float* __restrict__ Wt1, const float* __restrict__ bt1,
    const float* __restrict__ Wt2, const float* __restrict__ bt2,
    float* __restrict__ out_h, float* __restrict__ out_trust, int N)
{
    __shared__ float sWt1[32 * 16];
    __shared__ float sWt2[16];
    for (int i = threadIdx.x; i < 512; i += 256) sWt1[i] = Wt1[i];
    if (threadIdx.x < 16) sWt2[threadIdx.x] = Wt2[threadIdx.x];
    __syncthreads();

    int n = blockIdx.x * 16 + (threadIdx.x >> 4);
    int lane = threadIdx.x & 15;
    if (n >= N) return;

    int2 od = nodeOff[n];
    int beg = od.x, end = od.x + od.y;
    float lo0=0.f,hi0=0.f,lo1=0.f,hi1=0.f,lo2=0.f,hi2=0.f,lo3=0.f,hi3=0.f;
    int i = beg;
    for (; i + 4 <= end; i += 4) {
        int s0 = adj[i], s1 = adj[i+1], s2 = adj[i+2], s3 = adj[i+3];
        unsigned w0 = P16b[(size_t)s0 * 16 + lane];
        unsigned w1 = P16b[(size_t)s1 * 16 + lane];
        unsigned w2 = P16b[(size_t)s2 * 16 + lane];
        unsigned w3 = P16b[(size_t)s3 * 16 + lane];
        lo0 += bflo(w0); hi0 += bfhi(w0);
        lo1 += bflo(w1); hi1 += bfhi(w1);
        lo2 += bflo(w2); hi2 += bfhi(w2);
        lo3 += bflo(w3); hi3 += bfhi(w3);
    }
    for (; i < end; ++i) {
        unsigned w = P16b[(size_t)adj[i] * 16 + lane];
        lo0 += bflo(w); hi0 += bfhi(w);
    }
    float invd = (od.y > 0) ? 1.0f / (float)od.y : 1.0f;
    float2 qv = ((const float2*)Q)[(size_t)n * 16 + lane];
    float hx = ((lo0 + lo1) + (lo2 + lo3)) * invd + qv.x;   // col 2*lane
    float hy = ((hi0 + hi1) + (hi2 + hi3)) * invd + qv.y;   // col 2*lane+1

    ((float2*)out_h)[(size_t)n * 16 + lane] = make_float2(hx, hy);

    // trust: t_i = relu(bt1_i + sum_j h_j Wt1[j][i]);  z = sum_i t_i Wt2_i
    float t = bt1[lane];
    #pragma unroll
    for (int k = 0; k < 16; ++k) {
        float hlo = __shfl(hx, k, 16);
        float hhi = __shfl(hy, k, 16);
        t += hlo * sWt1[(2 * k) * 16 + lane] + hhi * sWt1[(2 * k + 1) * 16 + lane];
    }
    t = fmaxf(t, 0.0f);
    float z = t * sWt2[lane];
    z += __shfl_xor(z, 1);
    z += __shfl_xor(z, 2);
    z += __shfl_xor(z, 4);
    z += __shfl_xor(z, 8);
    if (lane == 0) out_trust[n] = 1.0f / (1.0f + expf(-(z + bt2[0])));
}

// ---------------------------------------------------------------------------

extern "C" void kernel_launch(void* const* d_in, const int* in_sizes, int n_in,
                              void* d_out, int out_size, void* d_ws, size_t ws_size,
                              hipStream_t stream)
{
    const float* x   = (const float*)d_in[0];
    const int*   ei  = (const int*)d_in[1];
    const float* Wl1 = (const float*)d_in[2];
    const float* Wr1 = (const float*)d_in[3];
    const float* b1  = (const float*)d_in[4];
    const float* Wl2 = (const float*)d_in[5];
    const float* Wr2 = (const float*)d_in[6];
    const float* b2  = (const float*)d_in[7];
    const float* Wt1 = (const float*)d_in[8];
    const float* bt1 = (const float*)d_in[9];
    const float* Wt2 = (const float*)d_in[10];
    const float* bt2 = (const float*)d_in[11];

    const int N = in_sizes[0] / 64;   // 100000
    const int E = in_sizes[1] / 2;    // 1600000
    const int* src = ei;
    const int* dst = ei + E;
    const int nbuck = (N + 511) / 512;       // 196

    // Workspace layout (all segments 64B-aligned)
    unsigned* pairs  = (unsigned*)d_ws;                        // nbuck*BCAP
    unsigned* u16b   = pairs + (size_t)nbuck * BCAP;           // N*32 (bf16 x2)
    float*    v      = (float*)(u16b + (size_t)N * 32);        // N*64 (h1 in-place)
    unsigned* P16b   = (unsigned*)(v + (size_t)N * 64);        // N*16 (bf16 x2)
    float*    Q      = (float*)(P16b + (size_t)N * 16);        // N*32
    int*      gcnt   = (int*)(Q + (size_t)N * 32);             // 256 (196 used)
    int2*     nodeOff= (int2*)(gcnt + 256);                    // N
    int*      adj    = (int*)(nodeOff + N);                    // nbuck*BCAP
    // total ~55 MB

    hipMemsetAsync(gcnt, 0, 256 * sizeof(int), stream);

    k_bucket<<<(E + BKCHUNK - 1) / BKCHUNK, 256, 0, stream>>>(src, dst, gcnt, pairs, E, nbuck);
    k_csr   <<<nbuck, 512, 0, stream>>>(pairs, gcnt, nodeOff, adj, N);

    const int GB = (N + 63) / 64;   // 1563 GEMM tiles
    k_gemm1<<<GB, 256, 0, stream>>>(x, Wl1, Wr1, b1, u16b, v, N);
    k_agg1 <<<(N + 7) / 8, 256, 0, stream>>>(nodeOff, adj, u16b, v, N);
    k_gemm2<<<GB, 256, 0, stream>>>(v, Wl2, Wr2, b2, P16b, Q, N);

    float* out_h     = (float*)d_out;
    float* out_trust = out_h + (size_t)N * 32;
    k_agg2 <<<(N + 15) / 16, 256, 0, stream>>>(nodeOff, adj, P16b, Q,
                                               Wt1, bt1, Wt2, bt2,
                                               out_h, out_trust, N);
}

// Round 7
// 248.855 us; speedup vs baseline: 4.8109x; 1.0623x over previous
//
#include <hip/hip_runtime.h>
#include <math.h>

// ---------------------------------------------------------------------------
// CommunityTrustGNN: 2-layer GraphSAGE (mean agg) + trust MLP head
// N=100000 nodes, E=1600000 edges, dims 64 -> 64 -> 32 -> (16 -> 1)
//
// Round 7:
//  * M1: k_bucket and k_gemm1 are independent (inputs only) -> ONE dispatch,
//    block-uniform branch. bucket alone was 391 blocks (1.5/CU, machine
//    idle); gemm1 fills it with complementary (FMA/LDS) work.
//  * M2: agg1 + gemm2 fused. Block owns 64 consecutive nodes; h1 lives in
//    LDS (never touches global: -51MB traffic), gemm2 tile runs from LDS.
//  * agg gather traffic itself is at the random-access L3 wall (92MB fetch
//    for 12.8MB array, ~2.6TB/s) - irreducible without fp8 (numerics risk).
// ---------------------------------------------------------------------------

#define BCAP    9216     // bucket capacity (mean 8192 for E=1.6M, +11 sigma)
#define BKCHUNK 4096     // edges per bucket-chunk block in M1

// bf16 helpers (round-to-nearest-even pack, exact unpack)
__device__ inline unsigned short f2bf(float x) {
    unsigned u = __float_as_uint(x);
    unsigned r = u + 0x7fffu + ((u >> 16) & 1u);
    return (unsigned short)(r >> 16);
}
__device__ inline unsigned pack2(float a, float b) {
    return (unsigned)f2bf(a) | ((unsigned)f2bf(b) << 16);
}
__device__ inline float bflo(unsigned u) { return __uint_as_float(u << 16); }
__device__ inline float bfhi(unsigned u) { return __uint_as_float(u & 0xffff0000u); }

// --- M1: blocks [0,GB) = gemm1 tile; blocks [GB,GB+BKB) = bucket scatter ----
// gemm1: u(bf16) = x@Wl1 ; v(f32) = x@Wr1 + b1   (64-node tile, 4x8/thread)
// bucket: edges -> packed (src | local_dst<<17), grouped by dst>>9
__global__ __launch_bounds__(256) void k_m1(
    const float* __restrict__ x,
    const float* __restrict__ Wl1, const float* __restrict__ Wr1,
    const float* __restrict__ b1,
    unsigned* __restrict__ u16b, float* __restrict__ v,
    const int* __restrict__ src, const int* __restrict__ dst,
    int* __restrict__ gcnt, unsigned* __restrict__ pairs,
    int N, int E, int nbuck, int GB)
{
    __shared__ __align__(16) char smem[50176];   // union: gemm1 49KB | hist 1KB
    int tid = threadIdx.x;

    if ((int)blockIdx.x >= GB) {
        // ---------------- bucket-scatter path ----------------
        int* hist = (int*)smem;
        int e0 = ((int)blockIdx.x - GB) * BKCHUNK;
        int e1 = min(e0 + BKCHUNK, E);

        hist[tid] = 0;
        __syncthreads();
        for (int e = e0 + tid; e < e1; e += 256)
            atomicAdd(&hist[((unsigned)dst[e]) >> 9], 1);
        __syncthreads();
        if (tid < nbuck && hist[tid] > 0)
            hist[tid] = tid * BCAP + atomicAdd(&gcnt[tid], hist[tid]);
        __syncthreads();
        for (int e = e0 + tid; e < e1; e += 256) {
            int t = dst[e];
            int b = ((unsigned)t) >> 9;
            int pos = atomicAdd(&hist[b], 1);
            pairs[pos] = (unsigned)src[e] | ((unsigned)(t & 511) << 17);
        }
        return;
    }

    // ---------------- gemm1 path ----------------
    float* sXT = (float*)smem;            // 64*68 [k][m]
    float* sW  = (float*)(smem + 17408);  // 64*128 [k][n]
    int nblk = blockIdx.x * 64;

    for (int i = tid * 4; i < 64 * 64; i += 1024) {
        int r = i >> 6, c = i & 63;
        int node = nblk + r;
        float4 xv = (node < N) ? *(const float4*)&x[(size_t)node * 64 + c]
                               : make_float4(0.f, 0.f, 0.f, 0.f);
        sXT[(c + 0) * 68 + r] = xv.x;
        sXT[(c + 1) * 68 + r] = xv.y;
        sXT[(c + 2) * 68 + r] = xv.z;
        sXT[(c + 3) * 68 + r] = xv.w;
    }
    for (int i = tid * 4; i < 64 * 128; i += 1024) {
        int k = i >> 7, n = i & 127;
        const float* Wsrc = (n < 64) ? (Wl1 + k * 64 + n) : (Wr1 + k * 64 + (n - 64));
        *(float4*)&sW[k * 128 + n] = *(const float4*)Wsrc;
    }
    __syncthreads();

    int mg = tid >> 4, ng = tid & 15;
    int m0 = mg * 4, n0 = ng * 8;

    float acc[4][8];
    #pragma unroll
    for (int mi = 0; mi < 4; ++mi)
        #pragma unroll
        for (int ni = 0; ni < 8; ++ni) acc[mi][ni] = 0.0f;

    #pragma unroll 8
    for (int k = 0; k < 64; ++k) {
        float4 a  = *(float4*)&sXT[k * 68 + m0];
        float4 w0 = *(float4*)&sW[k * 128 + n0];
        float4 w1 = *(float4*)&sW[k * 128 + n0 + 4];
        float av[4] = {a.x, a.y, a.z, a.w};
        float wv[8] = {w0.x, w0.y, w0.z, w0.w, w1.x, w1.y, w1.z, w1.w};
        #pragma unroll
        for (int mi = 0; mi < 4; ++mi)
            #pragma unroll
            for (int ni = 0; ni < 8; ++ni)
                acc[mi][ni] = fmaf(av[mi], wv[ni], acc[mi][ni]);
    }

    bool isV = (n0 >= 64);
    if (isV) {
        float4 b0 = *(const float4*)&b1[n0 - 64];
        float4 b4 = *(const float4*)&b1[n0 - 64 + 4];
        float bb[8] = {b0.x, b0.y, b0.z, b0.w, b4.x, b4.y, b4.z, b4.w};
        #pragma unroll
        for (int mi = 0; mi < 4; ++mi) {
            int node = nblk + m0 + mi;
            if (node >= N) continue;
            float* dstp = &v[(size_t)node * 64 + (n0 - 64)];
            *(float4*)&dstp[0] = make_float4(acc[mi][0]+bb[0], acc[mi][1]+bb[1],
                                             acc[mi][2]+bb[2], acc[mi][3]+bb[3]);
            *(float4*)&dstp[4] = make_float4(acc[mi][4]+bb[4], acc[mi][5]+bb[5],
                                             acc[mi][6]+bb[6], acc[mi][7]+bb[7]);
        }
    } else {
        #pragma unroll
        for (int mi = 0; mi < 4; ++mi) {
            int node = nblk + m0 + mi;
            if (node >= N) continue;
            uint4 pk;
            pk.x = pack2(acc[mi][0], acc[mi][1]);
            pk.y = pack2(acc[mi][2], acc[mi][3]);
            pk.z = pack2(acc[mi][4], acc[mi][5]);
            pk.w = pack2(acc[mi][6], acc[mi][7]);
            *(uint4*)&u16b[(size_t)node * 32 + (n0 >> 1)] = pk;
        }
    }
}

// --- fused CSR: per-bucket LDS histogram -> LDS scan -> LDS-cursor fill -----
__global__ __launch_bounds__(512) void k_csr(
    const unsigned* __restrict__ pairs, const int* __restrict__ gcnt,
    int2* __restrict__ nodeOff, int* __restrict__ adj, int N)
{
    __shared__ int hist[512];
    __shared__ int waveSum[8];
    int b = blockIdx.x;
    int tid = threadIdx.x;
    int count = min(gcnt[b], BCAP);
    const unsigned* pp = pairs + (size_t)b * BCAP;
    int base = b * BCAP;

    hist[tid] = 0;
    __syncthreads();
    for (int j = tid; j < count; j += 512)
        atomicAdd(&hist[pp[j] >> 17], 1);
    __syncthreads();

    int deg = hist[tid];
    int lane = tid & 63, wid = tid >> 6;
    int incl = deg;
    #pragma unroll
    for (int off = 1; off < 64; off <<= 1) {
        int t = __shfl_up(incl, off);
        if (lane >= off) incl += t;
    }
    if (lane == 63) waveSum[wid] = incl;
    __syncthreads();
    if (wid == 0 && lane < 8) {
        int s = waveSum[lane], orig = s;
        #pragma unroll
        for (int off = 1; off < 8; off <<= 1) {
            int t = __shfl_up(s, off);
            if (lane >= off) s += t;
        }
        waveSum[lane] = s - orig;
    }
    __syncthreads();
    int excl = incl - deg + waveSum[wid];

    int node = b * 512 + tid;
    if (node < N) nodeOff[node] = make_int2(base + excl, deg);
    __syncthreads();
    hist[tid] = excl;
    __syncthreads();

    for (int j = tid; j < count; j += 512) {
        unsigned e = pp[j];
        int pos = atomicAdd(&hist[e >> 17], 1);
        adj[base + pos] = (int)(e & 0x1FFFFu);
    }
}

// --- M2: agg1 + gemm2 fused. Block = 64 consecutive nodes, 512 threads. ----
// Phase A: 16 half-waves x 4 nodes: h1 = relu(mean(u[neigh]) + v) -> LDS sH.
// Phase B: 64x64 GEMM from sH: P(bf16,32)=h1@Wl2 ; Q(f32,32)=h1@Wr2+b2.
__global__ __launch_bounds__(512) void k_m2(
    const int2* __restrict__ nodeOff, const int* __restrict__ adj,
    const unsigned* __restrict__ u16b, const float* __restrict__ v,
    const float* __restrict__ Wl2, const float* __restrict__ Wr2,
    const float* __restrict__ b2,
    unsigned* __restrict__ P16b, float* __restrict__ Qout, int N)
{
    __shared__ float sH[64 * 66];    // [node][dim], stride 66 (bank-spread)
    __shared__ float sW[64 * 64];    // [k][n]: 0..31 Wl2, 32..63 Wr2
    int tid = threadIdx.x;
    int nodeBase = blockIdx.x * 64;

    // stage weights (overlaps with phase A's gathers before first barrier)
    for (int i = tid * 4; i < 64 * 64; i += 2048) {
        int k = i >> 6, n = i & 63;
        const float* Wsrc = (n < 32) ? (Wl2 + k * 32 + n) : (Wr2 + k * 32 + (n - 32));
        *(float4*)&sW[k * 64 + n] = *(const float4*)Wsrc;
    }

    // ---- Phase A: gather-aggregate 4 nodes per half-wave ----
    int hw = tid >> 5;          // 0..15
    int lane = tid & 31;
    #pragma unroll
    for (int r = 0; r < 4; ++r) {
        int nLoc = hw * 4 + r;
        int n = nodeBase + nLoc;
        float h0 = 0.0f, h1v = 0.0f;
        if (n < N) {
            int2 od = nodeOff[n];
            int beg = od.x, end = od.x + od.y;
            float lo0=0.f,hi0=0.f,lo1=0.f,hi1=0.f,lo2=0.f,hi2=0.f,lo3=0.f,hi3=0.f;
            int i = beg;
            for (; i + 4 <= end; i += 4) {
                int s0 = adj[i], s1 = adj[i+1], s2 = adj[i+2], s3 = adj[i+3];
                unsigned w0 = u16b[(size_t)s0 * 32 + lane];
                unsigned w1 = u16b[(size_t)s1 * 32 + lane];
                unsigned w2 = u16b[(size_t)s2 * 32 + lane];
                unsigned w3 = u16b[(size_t)s3 * 32 + lane];
                lo0 += bflo(w0); hi0 += bfhi(w0);
                lo1 += bflo(w1); hi1 += bfhi(w1);
                lo2 += bflo(w2); hi2 += bfhi(w2);
                lo3 += bflo(w3); hi3 += bfhi(w3);
            }
            for (; i < end; ++i) {
                unsigned w = u16b[(size_t)adj[i] * 32 + lane];
                lo0 += bflo(w); hi0 += bfhi(w);
            }
            float mlo = (lo0 + lo1) + (lo2 + lo3);
            float mhi = (hi0 + hi1) + (hi2 + hi3);
            float invd = (od.y > 0) ? 1.0f / (float)od.y : 1.0f;
            float2 vv = ((const float2*)v)[(size_t)n * 32 + lane];
            h0  = fmaxf(mlo * invd + vv.x, 0.0f);
            h1v = fmaxf(mhi * invd + vv.y, 0.0f);
        }
        *(float2*)&sH[nLoc * 66 + 2 * lane] = make_float2(h0, h1v);
    }
    __syncthreads();

    // ---- Phase B: 64x64 GEMM from LDS (each thread 2 rows x 4 cols) ----
    int ng = tid & 15;          // n0 = ng*4
    int mg = tid >> 4;          // 0..31, m0 = mg*2
    int m0 = mg * 2, n0 = ng * 4;

    float acc[2][4];
    #pragma unroll
    for (int mi = 0; mi < 2; ++mi)
        #pragma unroll
        for (int ni = 0; ni < 4; ++ni) acc[mi][ni] = 0.0f;

    #pragma unroll 8
    for (int k = 0; k < 64; ++k) {
        float a0 = sH[(m0 + 0) * 66 + k];
        float a1 = sH[(m0 + 1) * 66 + k];
        float4 w = *(float4*)&sW[k * 64 + n0];
        float wv[4] = {w.x, w.y, w.z, w.w};
        #pragma unroll
        for (int ni = 0; ni < 4; ++ni) {
            acc[0][ni] = fmaf(a0, wv[ni], acc[0][ni]);
            acc[1][ni] = fmaf(a1, wv[ni], acc[1][ni]);
        }
    }

    if (n0 < 32) {
        #pragma unroll
        for (int mi = 0; mi < 2; ++mi) {
            int node = nodeBase + m0 + mi;
            if (node >= N) continue;
            uint2 pk;
            pk.x = pack2(acc[mi][0], acc[mi][1]);
            pk.y = pack2(acc[mi][2], acc[mi][3]);
            *(uint2*)&P16b[(size_t)node * 16 + (n0 >> 1)] = pk;
        }
    } else {
        float4 b0 = *(const float4*)&b2[n0 - 32];
        #pragma unroll
        for (int mi = 0; mi < 2; ++mi) {
            int node = nodeBase + m0 + mi;
            if (node >= N) continue;
            *(float4*)&Qout[(size_t)node * 32 + (n0 - 32)] =
                make_float4(acc[mi][0]+b0.x, acc[mi][1]+b0.y,
                            acc[mi][2]+b0.z, acc[mi][3]+b0.w);
        }
    }
}

// --- agg2: h = mean(P[neigh]) + Q -> out_h ; trust head in-register ---------
// 16 lanes per node (lane = 1 uint = 2 cols); 64B fully-coalesced edge gather.
__global__ __launch_bounds__(256) void k_agg2(
    const int2* __restrict__ nodeOff, const int* __restrict__ adj,
    const unsigned* __restrict__ P16b, const float* __restrict__ Q,
    const float* __restrict__ Wt1, const float* __restrict__ bt1,
    const float* __restrict__ Wt2, const float* __restrict__ bt2,
    float* __restrict__ out_h, float* __restrict__ out_trust, int N)
{
    __shared__ float sWt1[32 * 16];
    __shared__ float sWt2[16];
    for (int i = threadIdx.x; i < 512; i += 256) sWt1[i] = Wt1[i];
    if (threadIdx.x < 16) sWt2[threadIdx.x] = Wt2[threadIdx.x];
    __syncthreads();

    int n = blockIdx.x * 16 + (threadIdx.x >> 4);
    int lane = threadIdx.x & 15;
    if (n >= N) return;

    int2 od = nodeOff[n];
    int beg = od.x, end = od.x + od.y;
    float lo0=0.f,hi0=0.f,lo1=0.f,hi1=0.f,lo2=0.f,hi2=0.f,lo3=0.f,hi3=0.f;
    int i = beg;
    for (; i + 4 <= end; i += 4) {
        int s0 = adj[i], s1 = adj[i+1], s2 = adj[i+2], s3 = adj[i+3];
        unsigned w0 = P16b[(size_t)s0 * 16 + lane];
        unsigned w1 = P16b[(size_t)s1 * 16 + lane];
        unsigned w2 = P16b[(size_t)s2 * 16 + lane];
        unsigned w3 = P16b[(size_t)s3 * 16 + lane];
        lo0 += bflo(w0); hi0 += bfhi(w0);
        lo1 += bflo(w1); hi1 += bfhi(w1);
        lo2 += bflo(w2); hi2 += bfhi(w2);
        lo3 += bflo(w3); hi3 += bfhi(w3);
    }
    for (; i < end; ++i) {
        unsigned w = P16b[(size_t)adj[i] * 16 + lane];
        lo0 += bflo(w); hi0 += bfhi(w);
    }
    float invd = (od.y > 0) ? 1.0f / (float)od.y : 1.0f;
    float2 qv = ((const float2*)Q)[(size_t)n * 16 + lane];
    float hx = ((lo0 + lo1) + (lo2 + lo3)) * invd + qv.x;
    float hy = ((hi0 + hi1) + (hi2 + hi3)) * invd + qv.y;

    ((float2*)out_h)[(size_t)n * 16 + lane] = make_float2(hx, hy);

    float t = bt1[lane];
    #pragma unroll
    for (int k = 0; k < 16; ++k) {
        float hlo = __shfl(hx, k, 16);
        float hhi = __shfl(hy, k, 16);
        t += hlo * sWt1[(2 * k) * 16 + lane] + hhi * sWt1[(2 * k + 1) * 16 + lane];
    }
    t = fmaxf(t, 0.0f);
    float z = t * sWt2[lane];
    z += __shfl_xor(z, 1);
    z += __shfl_xor(z, 2);
    z += __shfl_xor(z, 4);
    z += __shfl_xor(z, 8);
    if (lane == 0) out_trust[n] = 1.0f / (1.0f + expf(-(z + bt2[0])));
}

// ---------------------------------------------------------------------------

extern "C" void kernel_launch(void* const* d_in, const int* in_sizes, int n_in,
                              void* d_out, int out_size, void* d_ws, size_t ws_size,
                              hipStream_t stream)
{
    const float* x   = (const float*)d_in[0];
    const int*   ei  = (const int*)d_in[1];
    const float* Wl1 = (const float*)d_in[2];
    const float* Wr1 = (const float*)d_in[3];
    const float* b1  = (const float*)d_in[4];
    const float* Wl2 = (const float*)d_in[5];
    const float* Wr2 = (const float*)d_in[6];
    const float* b2  = (const float*)d_in[7];
    const float* Wt1 = (const float*)d_in[8];
    const float* bt1 = (const float*)d_in[9];
    const float* Wt2 = (const float*)d_in[10];
    const float* bt2 = (const float*)d_in[11];

    const int N = in_sizes[0] / 64;   // 100000
    const int E = in_sizes[1] / 2;    // 1600000
    const int* src = ei;
    const int* dst = ei + E;
    const int nbuck = (N + 511) / 512;       // 196

    // Workspace layout (all segments 64B-aligned)
    unsigned* pairs  = (unsigned*)d_ws;                        // nbuck*BCAP
    unsigned* u16b   = pairs + (size_t)nbuck * BCAP;           // N*32 (bf16 x2)
    float*    v      = (float*)(u16b + (size_t)N * 32);        // N*64
    unsigned* P16b   = (unsigned*)(v + (size_t)N * 64);        // N*16 (bf16 x2)
    float*    Q      = (float*)(P16b + (size_t)N * 16);        // N*32
    int*      gcnt   = (int*)(Q + (size_t)N * 32);             // 256 (196 used)
    int2*     nodeOff= (int2*)(gcnt + 256);                    // N
    int*      adj    = (int*)(nodeOff + N);                    // nbuck*BCAP
    // total ~55 MB

    hipMemsetAsync(gcnt, 0, 256 * sizeof(int), stream);

    const int GB  = (N + 63) / 64;               // 1563 gemm1 tiles
    const int BKB = (E + BKCHUNK - 1) / BKCHUNK; // 391 bucket chunks
    k_m1  <<<GB + BKB, 256, 0, stream>>>(x, Wl1, Wr1, b1, u16b, v,
                                         src, dst, gcnt, pairs, N, E, nbuck, GB);
    k_csr <<<nbuck, 512, 0, stream>>>(pairs, gcnt, nodeOff, adj, N);
    k_m2  <<<GB, 512, 0, stream>>>(nodeOff, adj, u16b, v, Wl2, Wr2, b2,
                                   P16b, Q, N);

    float* out_h     = (float*)d_out;
    float* out_trust = out_h + (size_t)N * 32;
    k_agg2<<<(N + 15) / 16, 256, 0, stream>>>(nodeOff, adj, P16b, Q,
                                              Wt1, bt1, Wt2, bt2,
                                              out_h, out_trust, N);
}

// Round 8
// 246.909 us; speedup vs baseline: 4.8488x; 1.0079x over previous
//
#include <hip/hip_runtime.h>
#include <math.h>

// ---------------------------------------------------------------------------
// CommunityTrustGNN: 2-layer GraphSAGE (mean agg) + trust MLP head
// N=100000 nodes, E=1600000 edges, dims 64 -> 64 -> 32 -> (16 -> 1)
//
// Round 8:
//  * m1: bucket blocks INTERLEAVED with gemm tiles (blockIdx%5==4) so both
//    kinds are resident from t=0 (round 7 appended them -> serialized).
//    gemm1 runs two 64-col passes -> LDS 50->33.8KB -> 4 blocks/CU.
//  * m2/agg2: neighbor-gather unroll 4->8 (halves dependent load rounds).
//  * csr: 1024 threads (halves per-thread serial iterations).
// ---------------------------------------------------------------------------

#define BCAP    9216     // bucket capacity (mean 8163 for E=1.6M)
#define BKCHUNK 4096     // edges per bucket-chunk block in M1

// bf16 helpers (round-to-nearest-even pack, exact unpack)
__device__ inline unsigned short f2bf(float x) {
    unsigned u = __float_as_uint(x);
    unsigned r = u + 0x7fffu + ((u >> 16) & 1u);
    return (unsigned short)(r >> 16);
}
__device__ inline unsigned pack2(float a, float b) {
    return (unsigned)f2bf(a) | ((unsigned)f2bf(b) << 16);
}
__device__ inline float bflo(unsigned u) { return __uint_as_float(u << 16); }
__device__ inline float bfhi(unsigned u) { return __uint_as_float(u & 0xffff0000u); }

// --- M1: interleaved gemm1 tiles + bucket-scatter chunks --------------------
// blockIdx%5==4 -> bucket chunk (blockIdx/5); else gemm tile 4*(b/5)+(b%5).
// gemm1: u(bf16) = x@Wl1 ; v(f32) = x@Wr1 + b1  (two 64-col passes)
// bucket: edges -> packed (src | local_dst<<17), grouped by dst>>9
__global__ __launch_bounds__(256) void k_m1(
    const float* __restrict__ x,
    const float* __restrict__ Wl1, const float* __restrict__ Wr1,
    const float* __restrict__ b1,
    unsigned* __restrict__ u16b, float* __restrict__ v,
    const int* __restrict__ src, const int* __restrict__ dst,
    int* __restrict__ gcnt, unsigned* __restrict__ pairs,
    int N, int E, int nbuck, int GB, int BKB)
{
    __shared__ __align__(16) char smem[33792]; // sXT 17408 + sW 16384 | hist 1KB
    int tid = threadIdx.x;
    int g = blockIdx.x / 5, r5 = blockIdx.x % 5;

    if (r5 == 4) {
        // ---------------- bucket-scatter path ----------------
        if (g >= BKB) return;
        int* hist = (int*)smem;
        int e0 = g * BKCHUNK;
        int e1 = min(e0 + BKCHUNK, E);

        hist[tid] = 0;
        __syncthreads();
        for (int e = e0 + tid; e < e1; e += 256)
            atomicAdd(&hist[((unsigned)dst[e]) >> 9], 1);
        __syncthreads();
        if (tid < nbuck && hist[tid] > 0)
            hist[tid] = tid * BCAP + atomicAdd(&gcnt[tid], hist[tid]);
        __syncthreads();
        for (int e = e0 + tid; e < e1; e += 256) {
            int t = dst[e];
            int b = ((unsigned)t) >> 9;
            int pos = atomicAdd(&hist[b], 1);
            pairs[pos] = (unsigned)src[e] | ((unsigned)(t & 511) << 17);
        }
        return;
    }

    // ---------------- gemm1 path ----------------
    int tile = 4 * g + r5;
    if (tile >= GB) return;
    float* sXT = (float*)smem;            // 64*68 [k][m]
    float* sW  = (float*)(smem + 17408);  // 64*64 [k][n], per pass
    int nblk = tile * 64;

    for (int i = tid * 4; i < 64 * 64; i += 1024) {
        int r = i >> 6, c = i & 63;
        int node = nblk + r;
        float4 xv = (node < N) ? *(const float4*)&x[(size_t)node * 64 + c]
                               : make_float4(0.f, 0.f, 0.f, 0.f);
        sXT[(c + 0) * 68 + r] = xv.x;
        sXT[(c + 1) * 68 + r] = xv.y;
        sXT[(c + 2) * 68 + r] = xv.z;
        sXT[(c + 3) * 68 + r] = xv.w;
    }

    int mg = tid >> 4, ng = tid & 15;
    int m0 = mg * 4, n0 = ng * 4;

    #pragma unroll
    for (int pass = 0; pass < 2; ++pass) {
        const float* W = pass ? Wr1 : Wl1;
        if (pass) __syncthreads();   // pass-0 reads done before restage
        for (int i = tid * 4; i < 64 * 64; i += 1024)
            *(float4*)&sW[i] = *(const float4*)&W[i];
        __syncthreads();

        float acc[4][4];
        #pragma unroll
        for (int mi = 0; mi < 4; ++mi)
            #pragma unroll
            for (int ni = 0; ni < 4; ++ni) acc[mi][ni] = 0.0f;

        #pragma unroll 8
        for (int k = 0; k < 64; ++k) {
            float4 a = *(float4*)&sXT[k * 68 + m0];
            float4 w = *(float4*)&sW[k * 64 + n0];
            float av[4] = {a.x, a.y, a.z, a.w};
            float wv[4] = {w.x, w.y, w.z, w.w};
            #pragma unroll
            for (int mi = 0; mi < 4; ++mi)
                #pragma unroll
                for (int ni = 0; ni < 4; ++ni)
                    acc[mi][ni] = fmaf(av[mi], wv[ni], acc[mi][ni]);
        }

        if (pass == 0) {
            #pragma unroll
            for (int mi = 0; mi < 4; ++mi) {
                int node = nblk + m0 + mi;
                if (node >= N) continue;
                uint2 pk;
                pk.x = pack2(acc[mi][0], acc[mi][1]);
                pk.y = pack2(acc[mi][2], acc[mi][3]);
                *(uint2*)&u16b[(size_t)node * 32 + (n0 >> 1)] = pk;
            }
        } else {
            float4 b0 = *(const float4*)&b1[n0];
            #pragma unroll
            for (int mi = 0; mi < 4; ++mi) {
                int node = nblk + m0 + mi;
                if (node >= N) continue;
                *(float4*)&v[(size_t)node * 64 + n0] =
                    make_float4(acc[mi][0]+b0.x, acc[mi][1]+b0.y,
                                acc[mi][2]+b0.z, acc[mi][3]+b0.w);
            }
        }
    }
}

// --- fused CSR: per-bucket LDS histogram -> LDS scan -> LDS-cursor fill -----
// One block (1024 thr) per bucket of 512 consecutive dst nodes.
__global__ __launch_bounds__(1024) void k_csr(
    const unsigned* __restrict__ pairs, const int* __restrict__ gcnt,
    int2* __restrict__ nodeOff, int* __restrict__ adj, int N)
{
    __shared__ int hist[512];
    __shared__ int waveSum[8];
    int b = blockIdx.x;
    int tid = threadIdx.x;
    int count = min(gcnt[b], BCAP);
    const unsigned* pp = pairs + (size_t)b * BCAP;
    int base = b * BCAP;

    if (tid < 512) hist[tid] = 0;
    __syncthreads();
    for (int j = tid; j < count; j += 1024)
        atomicAdd(&hist[pp[j] >> 17], 1);
    __syncthreads();

    int lane = tid & 63, wid = tid >> 6;
    int deg = 0, incl = 0;
    if (tid < 512) {
        deg = hist[tid];
        incl = deg;
        #pragma unroll
        for (int off = 1; off < 64; off <<= 1) {
            int t = __shfl_up(incl, off);
            if (lane >= off) incl += t;
        }
        if (lane == 63) waveSum[wid] = incl;
    }
    __syncthreads();
    if (wid == 0 && lane < 8) {
        int s = waveSum[lane], orig = s;
        #pragma unroll
        for (int off = 1; off < 8; off <<= 1) {
            int t = __shfl_up(s, off);
            if (lane >= off) s += t;
        }
        waveSum[lane] = s - orig;
    }
    __syncthreads();
    int excl = 0;
    if (tid < 512) {
        excl = incl - deg + waveSum[wid];
        int node = b * 512 + tid;
        if (node < N) nodeOff[node] = make_int2(base + excl, deg);
    }
    __syncthreads();
    if (tid < 512) hist[tid] = excl;
    __syncthreads();

    for (int j = tid; j < count; j += 1024) {
        unsigned e = pp[j];
        int pos = atomicAdd(&hist[e >> 17], 1);
        adj[base + pos] = (int)(e & 0x1FFFFu);
    }
}

// --- M2: agg1 + gemm2 fused. Block = 64 consecutive nodes, 512 threads. ----
// Phase A: 16 half-waves x 4 nodes: h1 = relu(mean(u[neigh]) + v) -> LDS sH.
// Phase B: 64x64 GEMM from sH: P(bf16,32)=h1@Wl2 ; Q(f32,32)=h1@Wr2+b2.
__global__ __launch_bounds__(512) void k_m2(
    const int2* __restrict__ nodeOff, const int* __restrict__ adj,
    const unsigned* __restrict__ u16b, const float* __restrict__ v,
    const float* __restrict__ Wl2, const float* __restrict__ Wr2,
    const float* __restrict__ b2,
    unsigned* __restrict__ P16b, float* __restrict__ Qout, int N)
{
    __shared__ float sH[64 * 66];    // [node][dim], stride 66
    __shared__ float sW[64 * 64];    // [k][n]: 0..31 Wl2, 32..63 Wr2
    int tid = threadIdx.x;
    int nodeBase = blockIdx.x * 64;

    for (int i = tid * 4; i < 64 * 64; i += 2048) {
        int k = i >> 6, n = i & 63;
        const float* Wsrc = (n < 32) ? (Wl2 + k * 32 + n) : (Wr2 + k * 32 + (n - 32));
        *(float4*)&sW[k * 64 + n] = *(const float4*)Wsrc;
    }

    // ---- Phase A: gather-aggregate 4 nodes per half-wave, 8-deep MLP ----
    int hw = tid >> 5;          // 0..15
    int lane = tid & 31;
    for (int r = 0; r < 4; ++r) {
        int nLoc = hw * 4 + r;
        int n = nodeBase + nLoc;
        float h0 = 0.0f, h1v = 0.0f;
        if (n < N) {
            int2 od = nodeOff[n];
            int beg = od.x, end = od.x + od.y;
            float lo[8] = {0,0,0,0,0,0,0,0}, hi[8] = {0,0,0,0,0,0,0,0};
            int i = beg;
            for (; i + 8 <= end; i += 8) {
                int s[8];
                #pragma unroll
                for (int j = 0; j < 8; ++j) s[j] = adj[i + j];
                #pragma unroll
                for (int j = 0; j < 8; ++j) {
                    unsigned w = u16b[(size_t)s[j] * 32 + lane];
                    lo[j] += bflo(w); hi[j] += bfhi(w);
                }
            }
            for (; i < end; ++i) {
                unsigned w = u16b[(size_t)adj[i] * 32 + lane];
                lo[0] += bflo(w); hi[0] += bfhi(w);
            }
            float mlo = ((lo[0]+lo[1])+(lo[2]+lo[3])) + ((lo[4]+lo[5])+(lo[6]+lo[7]));
            float mhi = ((hi[0]+hi[1])+(hi[2]+hi[3])) + ((hi[4]+hi[5])+(hi[6]+hi[7]));
            float invd = (od.y > 0) ? 1.0f / (float)od.y : 1.0f;
            float2 vv = ((const float2*)v)[(size_t)n * 32 + lane];
            h0  = fmaxf(mlo * invd + vv.x, 0.0f);
            h1v = fmaxf(mhi * invd + vv.y, 0.0f);
        }
        *(float2*)&sH[nLoc * 66 + 2 * lane] = make_float2(h0, h1v);
    }
    __syncthreads();

    // ---- Phase B: 64x64 GEMM from LDS (each thread 2 rows x 4 cols) ----
    int ng = tid & 15;
    int mg = tid >> 4;          // 0..31
    int m0 = mg * 2, n0 = ng * 4;

    float acc[2][4];
    #pragma unroll
    for (int mi = 0; mi < 2; ++mi)
        #pragma unroll
        for (int ni = 0; ni < 4; ++ni) acc[mi][ni] = 0.0f;

    #pragma unroll 8
    for (int k = 0; k < 64; ++k) {
        float a0 = sH[(m0 + 0) * 66 + k];
        float a1 = sH[(m0 + 1) * 66 + k];
        float4 w = *(float4*)&sW[k * 64 + n0];
        float wv[4] = {w.x, w.y, w.z, w.w};
        #pragma unroll
        for (int ni = 0; ni < 4; ++ni) {
            acc[0][ni] = fmaf(a0, wv[ni], acc[0][ni]);
            acc[1][ni] = fmaf(a1, wv[ni], acc[1][ni]);
        }
    }

    if (n0 < 32) {
        #pragma unroll
        for (int mi = 0; mi < 2; ++mi) {
            int node = nodeBase + m0 + mi;
            if (node >= N) continue;
            uint2 pk;
            pk.x = pack2(acc[mi][0], acc[mi][1]);
            pk.y = pack2(acc[mi][2], acc[mi][3]);
            *(uint2*)&P16b[(size_t)node * 16 + (n0 >> 1)] = pk;
        }
    } else {
        float4 b0 = *(const float4*)&b2[n0 - 32];
        #pragma unroll
        for (int mi = 0; mi < 2; ++mi) {
            int node = nodeBase + m0 + mi;
            if (node >= N) continue;
            *(float4*)&Qout[(size_t)node * 32 + (n0 - 32)] =
                make_float4(acc[mi][0]+b0.x, acc[mi][1]+b0.y,
                            acc[mi][2]+b0.z, acc[mi][3]+b0.w);
        }
    }
}

// --- agg2: h = mean(P[neigh]) + Q -> out_h ; trust head in-register ---------
// 16 lanes per node; 64B fully-coalesced edge gather, 8-deep MLP.
__global__ __launch_bounds__(256) void k_agg2(
    const int2* __restrict__ nodeOff, const int* __restrict__ adj,
    const unsigned* __restrict__ P16b, const float* __restrict__ Q,
    const float* __restrict__ Wt1, const float* __restrict__ bt1,
    const float* __restrict__ Wt2, const float* __restrict__ bt2,
    float* __restrict__ out_h, float* __restrict__ out_trust, int N)
{
    __shared__ float sWt1[32 * 16];
    __shared__ float sWt2[16];
    for (int i = threadIdx.x; i < 512; i += 256) sWt1[i] = Wt1[i];
    if (threadIdx.x < 16) sWt2[threadIdx.x] = Wt2[threadIdx.x];
    __syncthreads();

    int n = blockIdx.x * 16 + (threadIdx.x >> 4);
    int lane = threadIdx.x & 15;
    if (n >= N) return;

    int2 od = nodeOff[n];
    int beg = od.x, end = od.x + od.y;
    float lo[8] = {0,0,0,0,0,0,0,0}, hi[8] = {0,0,0,0,0,0,0,0};
    int i = beg;
    for (; i + 8 <= end; i += 8) {
        int s[8];
        #pragma unroll
        for (int j = 0; j < 8; ++j) s[j] = adj[i + j];
        #pragma unroll
        for (int j = 0; j < 8; ++j) {
            unsigned w = P16b[(size_t)s[j] * 16 + lane];
            lo[j] += bflo(w); hi[j] += bfhi(w);
        }
    }
    for (; i < end; ++i) {
        unsigned w = P16b[(size_t)adj[i] * 16 + lane];
        lo[0] += bflo(w); hi[0] += bfhi(w);
    }
    float invd = (od.y > 0) ? 1.0f / (float)od.y : 1.0f;
    float mlo = (((lo[0]+lo[1])+(lo[2]+lo[3])) + ((lo[4]+lo[5])+(lo[6]+lo[7]))) * invd;
    float mhi = (((hi[0]+hi[1])+(hi[2]+hi[3])) + ((hi[4]+hi[5])+(hi[6]+hi[7]))) * invd;

    float2 qv = ((const float2*)Q)[(size_t)n * 16 + lane];
    float hx = mlo + qv.x;
    float hy = mhi + qv.y;

    ((float2*)out_h)[(size_t)n * 16 + lane] = make_float2(hx, hy);

    float t = bt1[lane];
    #pragma unroll
    for (int k = 0; k < 16; ++k) {
        float hlo = __shfl(hx, k, 16);
        float hhi = __shfl(hy, k, 16);
        t += hlo * sWt1[(2 * k) * 16 + lane] + hhi * sWt1[(2 * k + 1) * 16 + lane];
    }
    t = fmaxf(t, 0.0f);
    float z = t * sWt2[lane];
    z += __shfl_xor(z, 1);
    z += __shfl_xor(z, 2);
    z += __shfl_xor(z, 4);
    z += __shfl_xor(z, 8);
    if (lane == 0) out_trust[n] = 1.0f / (1.0f + expf(-(z + bt2[0])));
}

// ---------------------------------------------------------------------------

extern "C" void kernel_launch(void* const* d_in, const int* in_sizes, int n_in,
                              void* d_out, int out_size, void* d_ws, size_t ws_size,
                              hipStream_t stream)
{
    const float* x   = (const float*)d_in[0];
    const int*   ei  = (const int*)d_in[1];
    const float* Wl1 = (const float*)d_in[2];
    const float* Wr1 = (const float*)d_in[3];
    const float* b1  = (const float*)d_in[4];
    const float* Wl2 = (const float*)d_in[5];
    const float* Wr2 = (const float*)d_in[6];
    const float* b2  = (const float*)d_in[7];
    const float* Wt1 = (const float*)d_in[8];
    const float* bt1 = (const float*)d_in[9];
    const float* Wt2 = (const float*)d_in[10];
    const float* bt2 = (const float*)d_in[11];

    const int N = in_sizes[0] / 64;   // 100000
    const int E = in_sizes[1] / 2;    // 1600000
    const int* src = ei;
    const int* dst = ei + E;
    const int nbuck = (N + 511) / 512;       // 196

    // Workspace layout (all segments 64B-aligned)
    unsigned* pairs  = (unsigned*)d_ws;                        // nbuck*BCAP
    unsigned* u16b   = pairs + (size_t)nbuck * BCAP;           // N*32 (bf16 x2)
    float*    v      = (float*)(u16b + (size_t)N * 32);        // N*64
    unsigned* P16b   = (unsigned*)(v + (size_t)N * 64);        // N*16 (bf16 x2)
    float*    Q      = (float*)(P16b + (size_t)N * 16);        // N*32
    int*      gcnt   = (int*)(Q + (size_t)N * 32);             // 256 (196 used)
    int2*     nodeOff= (int2*)(gcnt + 256);                    // N
    int*      adj    = (int*)(nodeOff + N);                    // nbuck*BCAP
    // total ~55 MB

    hipMemsetAsync(gcnt, 0, 256 * sizeof(int), stream);

    const int GB  = (N + 63) / 64;               // 1563 gemm1 tiles
    const int BKB = (E + BKCHUNK - 1) / BKCHUNK; // 391 bucket chunks
    int grp = max(BKB, (GB + 3) / 4);            // 391
    k_m1  <<<5 * grp, 256, 0, stream>>>(x, Wl1, Wr1, b1, u16b, v,
                                        src, dst, gcnt, pairs, N, E, nbuck, GB, BKB);
    k_csr <<<nbuck, 1024, 0, stream>>>(pairs, gcnt, nodeOff, adj, N);
    k_m2  <<<GB, 512, 0, stream>>>(nodeOff, adj, u16b, v, Wl2, Wr2, b2,
                                   P16b, Q, N);

    float* out_h     = (float*)d_out;
    float* out_trust = out_h + (size_t)N * 32;
    k_agg2<<<(N + 15) / 16, 256, 0, stream>>>(nodeOff, adj, P16b, Q,
                                              Wt1, bt1, Wt2, bt2,
                                              out_h, out_trust, N);
}